// Round 3
// baseline (1436.315 us; speedup 1.0000x reference)
//
#include <hip/hip_runtime.h>

typedef unsigned int u32;
typedef unsigned short u16;
typedef float f32x2 __attribute__((ext_vector_type(2)));

#define BG 64
#define NNODE 320
#define NEDGE 1280
#define TT 256
#define FN 64
#define FG 16
#define HM 128
#define HU 128
#define HG 64
#define HA 4
#define ZM 512
#define ZU 512
#define ZG 256
#define ZA 16
#define DM 144
#define DU 208
#define DG 144
#define DA 192

// ---- conversion-area layout (floats, relative to ws+64) ----
#define CV 64
#define O_NODES 0
#define O_GA    20480
#define O_WM    21504
#define O_WHM   95232
#define O_BM    160768
#define O_WU    161280
#define O_WHU   267776
#define O_BU    333312
#define O_WG    333824
#define O_WHG   370688
#define O_BG2   387072
#define O_WA    387328
#define O_WHA   390400
#define O_BA    390464
#define CONV_TOTAL 390480
#define O_XZM   390528
#define O_XZU   (O_XZM + NEDGE * ZM)
#define O_XZG   (O_XZU + NNODE * ZU)
#define O_XZA   (O_XZG + BG * ZG)
#define O_AGGR  (O_XZA + BG * ZA)
#define O_AGGB  (O_AGGR + NNODE * HM)
#define O_UPD   (O_AGGB + BG * HU)
#define WS_FLOATS (CV + O_UPD + NNODE * HU)

__device__ __forceinline__ float bf2f(u16 v) {
  return __uint_as_float(((u32)v) << 16);
}
__device__ __forceinline__ float rcp_(float x) { return __builtin_amdgcn_rcpf(x); }
__device__ __forceinline__ float sigf(float x) { return rcp_(1.0f + __expf(-x)); }
__device__ __forceinline__ float tanh_(float x) {
  float e = __expf(-2.0f * fabsf(x));
  float t = (1.0f - e) * rcp_(1.0f + e);
  return copysignf(t, x);
}
__device__ __forceinline__ float cvt(const void* p, int i, int flag) {
  return flag ? bf2f(((const u16*)p)[i]) : ((const float*)p)[i];
}

// DPP cross-lane move (pure VALU, no DS pipe). quad_perm encodings:
// 0xB1 = [1,0,3,2] (lane^1), 0x4E = [2,3,0,1] (lane^2), 0x1B = [3,2,1,0] (lane^3).
template <int CTRL>
__device__ __forceinline__ float dppmov(float s) {
  return __int_as_float(
      __builtin_amdgcn_update_dpp(0, __float_as_int(s), CTRL, 0xF, 0xF, true));
}

// Packed 2xfp32 FMA (gfx90a+): one issue slot for two MACs. "v" constraints
// force arch-VGPR operands (an f32x2 maps to an even-aligned VGPR pair).
#define PKFMA(acc, w, h) \
  asm("v_pk_fma_f32 %0, %1, %2, %0" : "+v"(acc) : "v"(w), "v"(h))

// Arch-residency pin: every weight pair is an in/out "v" operand of an empty
// asm inside the loop. Regalloc must have each value in an arch VGPR at this
// point every iteration -> keeping them resident in arch VGPRs is the only
// allocation that avoids per-iteration copies. (Rounds 0-2 showed the weight
// tile being AGPR-spilled: VGPR_Count 84/48/52 with a 64-float array, costing
// one accvgpr-read per MAC.)
#define PIN32(w) \
  asm volatile("" \
    : "+v"(w[0]), "+v"(w[1]), "+v"(w[2]), "+v"(w[3]), \
      "+v"(w[4]), "+v"(w[5]), "+v"(w[6]), "+v"(w[7]), \
      "+v"(w[8]), "+v"(w[9]), "+v"(w[10]), "+v"(w[11]), \
      "+v"(w[12]), "+v"(w[13]), "+v"(w[14]), "+v"(w[15]), \
      "+v"(w[16]), "+v"(w[17]), "+v"(w[18]), "+v"(w[19]), \
      "+v"(w[20]), "+v"(w[21]), "+v"(w[22]), "+v"(w[23]), \
      "+v"(w[24]), "+v"(w[25]), "+v"(w[26]), "+v"(w[27]), \
      "+v"(w[28]), "+v"(w[29]), "+v"(w[30]), "+v"(w[31]))

// lgkmcnt-only barrier: LDS ordering without the vmcnt(0) drain that
// __syncthreads() emits. Global ops here are fire-and-forget stores (consumed
// by later kernels; visible at dispatch end) and prefetch loads (compiler
// inserts vmcnt wait at first use). See k_chain ordering proof in comments.
#define BAR() asm volatile("s_waitcnt lgkmcnt(0)\n\ts_barrier" ::: "memory")

// ---------------------------------------------------------------------------
// K-1: runtime dtype detector (unchanged; fp32 was detected).
// ---------------------------------------------------------------------------
__global__ void k_detect(const u32* __restrict__ raw, int* __restrict__ flagp) {
  const int t = threadIdx.x;  // 64 threads (1 wave)
  int zlo = 0, hits = 0;
  for (int k = t; k < 256; k += 64) {
    u32 w = raw[k];
    if ((w & 0xFFFFu) == 0u) zlo++;
    u32 m = (w >> 8) & 0x7Fu;
    if (m >= 40u && m <= 70u) hits++;
  }
#pragma unroll
  for (int off = 32; off; off >>= 1) {
    zlo += __shfl_down(zlo, off, 64);
    hits += __shfl_down(hits, off, 64);
  }
  if (t == 0) *flagp = (zlo < 128 && hits >= 128) ? 1 : 0;
}

// ---------------------------------------------------------------------------
// K0: convert weights/biases (+ t=255 slices) to fp32 in workspace.
// ---------------------------------------------------------------------------
__global__ __launch_bounds__(256) void k_convert(
    const void* nodes, const void* gattr,
    const void* Wm, const void* Whm, const void* bm1, const void* bm2,
    const void* Wu, const void* Whu, const void* bu1, const void* bu2,
    const void* Wg, const void* Whg, const void* bg1, const void* bg2,
    const void* Wa, const void* Wha, const void* ba1, const void* ba2,
    const int* __restrict__ flagp, float* __restrict__ dst) {
  const int flag = *flagp;
  const int i = blockIdx.x * 256 + threadIdx.x;
  if (i >= CONV_TOTAL) return;
  float v;
  if (i < O_GA) {
    int n = i >> 6, f = i & 63;
    v = cvt(nodes, (n * TT + (TT - 1)) * FN + f, flag);
  } else if (i < O_WM) {
    int l = i - O_GA; int b = l >> 4, g = l & 15;
    v = cvt(gattr, (b * TT + (TT - 1)) * FG + g, flag);
  } else if (i < O_BM) {
    v = (i < O_WHM) ? cvt(Wm, i - O_WM, flag) : cvt(Whm, i - O_WHM, flag);
  } else if (i < O_WU) {
    int l = i - O_BM; v = cvt(bm1, l, flag) + cvt(bm2, l, flag);
  } else if (i < O_BU) {
    v = (i < O_WHU) ? cvt(Wu, i - O_WU, flag) : cvt(Whu, i - O_WHU, flag);
  } else if (i < O_WG) {
    int l = i - O_BU; v = cvt(bu1, l, flag) + cvt(bu2, l, flag);
  } else if (i < O_BG2) {
    v = (i < O_WHG) ? cvt(Wg, i - O_WG, flag) : cvt(Whg, i - O_WHG, flag);
  } else if (i < O_WA) {
    int l = i - O_BG2; v = cvt(bg1, l, flag) + cvt(bg2, l, flag);
  } else if (i < O_WHA) {
    v = cvt(Wa, i - O_WA, flag);
  } else if (i < O_BA) {
    v = cvt(Wha, i - O_WHA, flag);
  } else {
    int l = i - O_BA; v = cvt(ba1, l, flag) + cvt(ba2, l, flag);
  }
  dst[i] = v;
}

// ---------------------------------------------------------------------------
// K1: parallel precompute of input projections at t = T-1 (unchanged).
// ---------------------------------------------------------------------------
__global__ __launch_bounds__(256) void k_pre(
    const float* __restrict__ cva,
    const int* __restrict__ eidx, const int* __restrict__ num_nodes,
    const int* __restrict__ num_edges,
    float* __restrict__ XZm, float* __restrict__ XZu, float* __restrict__ XZg) {
  const int blk = blockIdx.x, tid = threadIdx.x;
  __shared__ float xv[FN];
  __shared__ float gav[FG];
  __shared__ int sgr;
  const float* nodes255 = cva + O_NODES;
  const float* ga255 = cva + O_GA;

  if (blk < NEDGE) {
    const int e = blk;
    if (tid == 0) {
      int g = 0, acc = 0;
      while (g < BG) { int c = num_edges[g]; if (e < acc + c) break; acc += c; ++g; }
      if (g >= BG) g = BG - 1;
      sgr = g;
    }
    const int srcn = eidx[e];  // faithful: src == tgt == edge_indices[0]
    if (tid < FN) xv[tid] = nodes255[srcn * FN + tid];
    __syncthreads();
    if (tid < FG) gav[tid] = ga255[sgr * FG + tid];
    __syncthreads();
    for (int j = tid; j < ZM; j += 256) {
      const float* wr = cva + O_WM + j * DM;
      float acc = cva[O_BM + j];
#pragma unroll
      for (int d = 0; d < FN; ++d) acc += (wr[d] + wr[FN + d]) * xv[d];
#pragma unroll
      for (int d = 0; d < FG; ++d) acc += wr[2 * FN + d] * gav[d];
      XZm[(size_t)e * ZM + j] = acc;
    }
  } else if (blk < NEDGE + NNODE) {
    const int n = blk - NEDGE;
    if (tid == 0) {
      int g = 0, acc = 0;
      while (g < BG) { int c = num_nodes[g]; if (n < acc + c) break; acc += c; ++g; }
      if (g >= BG) g = BG - 1;
      sgr = g;
    }
    if (tid < FN) xv[tid] = nodes255[n * FN + tid];
    __syncthreads();
    if (tid < FG) gav[tid] = ga255[sgr * FG + tid];
    __syncthreads();
    for (int j = tid; j < ZU; j += 256) {
      const float* wr = cva + O_WU + j * DU;
      float acc = cva[O_BU + j];
#pragma unroll
      for (int d = 0; d < FN; ++d) acc += wr[d] * xv[d];
#pragma unroll
      for (int d = 0; d < FG; ++d) acc += wr[FN + HM + d] * gav[d];
      XZu[(size_t)n * ZU + j] = acc;
    }
  } else {
    const int b = blk - NEDGE - NNODE;
    if (tid < FG) gav[tid] = ga255[b * FG + tid];
    __syncthreads();
    if (tid < ZG) {
      const float* wr = cva + O_WG + tid * DG;
      float acc = cva[O_BG2 + tid];
#pragma unroll
      for (int d = 0; d < FG; ++d) acc += wr[HU + d] * gav[d];
      XZg[(size_t)b * ZG + tid] = acc;
    }
  }
}

// ---------------------------------------------------------------------------
// K2/K4: LSTM chain. 1024 threads (16 waves), issue-count-minimized form.
//
// Layout: 8-lane group = {quad q, quad q^32}: kc = (lane&3)|((lane&32)>>3)
// selects a 16-float k-chunk of h; elem = wv*8 + ((lane>>2)&7). Each lane
// computes 4 gate-partials as 8 v_pk_fma_f32 per gate (32 pk total = 64
// MACs), then a 3-round REDUCE-SCATTER (^1, ^2 via quad_perm DPP; ^32 via
// shfl) leaves z[gate p = lane&3] one-per-lane. Each lane runs ONE unified
// nonlinearity; c/h assembled in p==0 lanes via 3 quad_perm gathers.
// Weight pairs are pinned to arch VGPRs via PIN32 (see macro comment).
//
// h double-buffered in LDS: 8 chunks x 20 floats (16 + 4 pad); the 8
// distinct b128 read addresses cover all 32 banks exactly once.
// Ordering proof for overlay (k_msg: hout overlays XZ region):
//   store of step e-1's h at step e touches XZ floats [(e-1)*128,(e)*128)
//   i.e. XZ row (e-1)/4 <= e-1; every wave consumed that row's loads
//   (vmcnt-waited at its z compute) before passing barrier e-1; prefetch at
//   step e reads row e+1 > (e-1)/4. No in-flight load can see the store.
//   Unconditional prefetch of row STEPS reads one row past XZ: still inside
//   the workspace (XZu follows XZm, XZg follows XZu); value unused.
// ---------------------------------------------------------------------------
template <int STEPS>
__global__ __launch_bounds__(1024, 4) void k_chain(
    const float* __restrict__ Whh, const float* __restrict__ XZ,
    float* __restrict__ hout) {
  const int lane = threadIdx.x & 63;
  const int wv = threadIdx.x >> 6;               // wave 0..15
  const int p = lane & 3;                        // gate this lane finalizes
  const int kc = (lane & 3) | ((lane & 32) >> 3);  // k-chunk 0..7
  const int elem = wv * 8 + ((lane >> 2) & 7);   // element 0..127
  const bool islead = (p == 0) && (lane < 32);   // 1 lane per element
  __shared__ float hbuf[2][160];                 // 8 chunks x (16 + 4 pad)

  f32x2 w[32];  // Whh rows {pp*128+elem}, cols kc*16..+15, as 8 pairs/gate
#pragma unroll
  for (int pp = 0; pp < 4; ++pp) {
    const float4* wr =
        (const float4*)(Whh + (size_t)(pp * 128 + elem) * 128 + kc * 16);
#pragma unroll
    for (int q = 0; q < 4; ++q) {
      float4 t = wr[q];
      f32x2 lo, hi;
      lo.x = t.x; lo.y = t.y; hi.x = t.z; hi.y = t.w;
      w[pp * 8 + 2 * q] = lo;
      w[pp * 8 + 2 * q + 1] = hi;
    }
  }
  // per-lane nonlinearity constants: sigmoid(z)=rcp(1+exp2(-z*log2e));
  // tanh(z)=2*rcp(1+exp2(-2z*log2e))-1. Unified: fma(smul, rcp(1+exp2(z*kmul)), badd)
  const float LOG2E = 1.4426950408889634f;
  const float kmul = (p == 2) ? (-2.0f * LOG2E) : (-LOG2E);
  const float smul = (p == 2) ? 2.0f : 1.0f;
  const float badd = (p == 2) ? -1.0f : 0.0f;
  const float KT2 = -2.0f * LOG2E;  // for tanh(c)

  if (threadIdx.x < 160) hbuf[0][threadIdx.x] = 0.0f;
  float c = 0.0f;
  float hrelu_prev = 0.0f;
  float xz = XZ[p * 128 + elem];
  BAR();
  int cur = 0;
  for (int e = 0; e < STEPS; ++e) {
    PIN32(w);
    // h chunk (16 floats) from LDS, conflict-free b128 broadcast
    f32x2 hv2[8];
    const float4* hb = (const float4*)&hbuf[cur][kc * 20];
#pragma unroll
    for (int q = 0; q < 4; ++q) {
      float4 t = hb[q];
      hv2[2 * q].x = t.x; hv2[2 * q].y = t.y;
      hv2[2 * q + 1].x = t.z; hv2[2 * q + 1].y = t.w;
    }
    // 4 packed fmac chains (1 per gate), arch-VGPR pinned: 32 pk = 64 MACs
    f32x2 a0, a1, a2, a3;
    a0.x = 0.0f; a0.y = 0.0f; a1 = a0; a2 = a0; a3 = a0;
#pragma unroll
    for (int k = 0; k < 8; ++k) {
      PKFMA(a0, w[0 * 8 + k], hv2[k]);
      PKFMA(a1, w[1 * 8 + k], hv2[k]);
      PKFMA(a2, w[2 * 8 + k], hv2[k]);
      PKFMA(a3, w[3 * 8 + k], hv2[k]);
    }
    float pa0 = a0.x + a0.y, pa1 = a1.x + a1.y;
    float pa2 = a2.x + a2.y, pa3 = a3.x + a3.y;
    // reduce-scatter: after this, z holds gate (lane&3) of elem, summed
    // over the 8-lane group. Exchange pattern: send my DISCARDED value
    // (= partner's kept gate), receive partner's discarded (= my kept).
    const bool o0 = (lane & 1) != 0, o1 = (lane & 2) != 0;
    float u0 = o0 ? pa1 : pa0, d0 = o0 ? pa0 : pa1;
    float u1 = o0 ? pa3 : pa2, d1 = o0 ? pa2 : pa3;
    u0 += dppmov<0xB1>(d0);
    u1 += dppmov<0xB1>(d1);
    float uu = o1 ? u1 : u0, dd = o1 ? u0 : u1;
    uu += dppmov<0x4E>(dd);
    float z = uu + __shfl_xor(uu, 32, 64) + xz;
    // prefetch next step's xz (own gate only; vmcnt at next use)
    xz = XZ[(size_t)(e + 1) * 512 + p * 128 + elem];
    // unified per-lane gate nonlinearity
    float ex = __builtin_amdgcn_exp2f(z * kmul);
    float gq = __builtin_fmaf(smul, rcp_(1.0f + ex), badd);
    // assemble c,h in p==0 lanes (others compute garbage, never read)
    float gf = dppmov<0xB1>(gq);  // sigmoid(zf) from lane^1
    float gt = dppmov<0x4E>(gq);  // tanh(zg)    from lane^2
    float go = dppmov<0x1B>(gq);  // sigmoid(zo) from lane^3
    c = __builtin_fmaf(gf, c, gq * gt);
    float ec = __builtin_amdgcn_exp2f(c * KT2);
    float th = __builtin_fmaf(2.0f, rcp_(1.0f + ec), -1.0f);
    float h = go * th;
    if (islead) {
      hbuf[cur ^ 1][(elem >> 4) * 20 + (elem & 15)] = h;
      if (e > 0) hout[(size_t)(e - 1) * 128 + elem] = hrelu_prev;
      hrelu_prev = fmaxf(h, 0.0f);
    }
    BAR();
    cur ^= 1;
  }
  if (islead) hout[(size_t)(STEPS - 1) * 128 + elem] = hrelu_prev;
}

// ---------------------------------------------------------------------------
// K3: fused segment_min over edges + aggr projection (was k_aggmin+k_aggproj;
// aggr never leaves the block). Block n: phase 1 (threads 0..127) computes
// aggr[n][j] = min over edges with eidx==n; phase 2 (all 256) does
// XZu[n] += Wih_u[:,64:192] @ aggr.
// ---------------------------------------------------------------------------
__global__ __launch_bounds__(256) void k_aggminproj(
    const float* __restrict__ cva, const float* __restrict__ msg,
    const int* __restrict__ eidx, float* __restrict__ XZu) {
  const int n = blockIdx.x, tid = threadIdx.x;
  __shared__ float av[HM];
  if (tid < HM) {
    float m = __uint_as_float(0x7f800000u);  // +inf (segment_min identity)
    for (int e = 0; e < NEDGE; ++e) {
      if (eidx[e] == n) m = fminf(m, msg[(size_t)e * HM + tid]);
    }
    av[tid] = m;
  }
  __syncthreads();
  for (int j = tid; j < ZU; j += 256) {
    const float* wr = cva + O_WU + j * DU + FN;
    float acc = 0.0f;
#pragma unroll
    for (int k = 0; k < HM; ++k) acc += wr[k] * av[k];
    XZu[(size_t)n * ZU + j] += acc;
  }
}

// ---------------------------------------------------------------------------
// K5: fused (was k_aggbmin+k_gproj; aggB computed in-block, never global).
// blocks [0,64): aggB[b] = segmin(upd) -> XZg[b] += Wih_g[:,0:128] @ aggB[b]
// blocks [64,128): chosen[b] -> XZa[b] = Wih_a[:,0:128] @ chosen[b] + biases
// ---------------------------------------------------------------------------
__global__ __launch_bounds__(256) void k_gproj(
    const float* __restrict__ cva, const float* __restrict__ upd,
    const int* __restrict__ bidx, const int* __restrict__ who,
    float* __restrict__ XZg, float* __restrict__ XZa) {
  const int blk = blockIdx.x, tid = threadIdx.x;
  __shared__ float buf[HU];
  __shared__ int satbw;
  if (blk < BG) {
    const int b = blk;
    if (tid < HU) {
      float m = __uint_as_float(0x7f800000u);
      for (int n = 0; n < NNODE; ++n) {
        if (bidx[n] == b) m = fminf(m, upd[(size_t)n * HU + tid]);
      }
      buf[tid] = m;
    }
    __syncthreads();
    if (tid < ZG) {
      const float* wr = cva + O_WG + tid * DG;
      float acc = 0.0f;
#pragma unroll
      for (int k = 0; k < HU; ++k) acc += wr[k] * buf[k];
      XZg[(size_t)b * ZG + tid] += acc;
    }
  } else {
    const int b = blk - BG;
    const int whoB = who[b];
    if (tid == 0) {
      int off = 0;
      for (int i = 0; i < NNODE; ++i) off += (bidx[i] < b) ? 1 : 0;
      const int adj = (whoB == 3) ? 2 : whoB;
      satbw = (b == 0) ? who[0] : (adj + off);
    }
    if (whoB == 3) {
      if (tid < HU) {
        float m = __uint_as_float(0x7f800000u);
        for (int n = 0; n < NNODE; ++n) {
          if (bidx[n] == b) m = fminf(m, upd[(size_t)n * HU + tid]);
        }
        buf[tid] = m;
      }
      __syncthreads();
    } else {
      __syncthreads();
      if (tid < HU) buf[tid] = upd[(size_t)satbw * HU + tid];
      __syncthreads();
    }
    if (tid < ZA) {
      const float* wr = cva + O_WA + tid * DA;
      float acc = cva[O_BA + tid];
#pragma unroll
      for (int k = 0; k < HU; ++k) acc += wr[k] * buf[k];
      XZa[(size_t)b * ZA + tid] = acc;
    }
  }
}

// ---------------------------------------------------------------------------
// K6: group LSTM chain (64 steps, H=64) + action chain + softmax + fp32 out.
// ---------------------------------------------------------------------------
__global__ __launch_bounds__(256, 2) void k_final(
    const float* __restrict__ cva, const float* __restrict__ XZg,
    const float* __restrict__ XZa, float* __restrict__ out) {
  const int j = threadIdx.x;
  __shared__ __align__(16) float hg[HG];
  __shared__ float zsg[ZG];
  __shared__ float grp[BG * HG];
  __shared__ float za[ZA];
  __shared__ float haL[HA];
  __shared__ float res[BG * HA];

  float wg[HG];
  {
    const float* wr = cva + O_WHG + j * HG;
#pragma unroll
    for (int k = 0; k < HG; ++k) wg[k] = wr[k];
  }
  if (j < HG) hg[j] = 0.0f;
  float cg = 0.0f;
  __syncthreads();
  for (int b = 0; b < BG; ++b) {
    float acc = XZg[(size_t)b * ZG + j];
#pragma unroll
    for (int k = 0; k < HG; ++k) acc += wg[k] * hg[k];
    zsg[j] = acc;
    __syncthreads();
    if (j < HG) {
      float zi = zsg[j], zf = zsg[HG + j], zg = zsg[2 * HG + j], zo = zsg[3 * HG + j];
      cg = sigf(zf) * cg + sigf(zi) * tanh_(zg);
      float h = sigf(zo) * tanh_(cg);
      hg[j] = h;
      grp[b * HG + j] = fmaxf(h, 0.0f);
    }
    __syncthreads();
  }

  float wa2[HG];
  float wha[HA];
  if (j < ZA) {
    const float* wr2 = cva + O_WA + j * DA + HU;
#pragma unroll
    for (int k = 0; k < HG; ++k) wa2[k] = wr2[k];
#pragma unroll
    for (int k = 0; k < HA; ++k) wha[k] = cva[O_WHA + j * HA + k];
  }
  if (j < HA) haL[j] = 0.0f;
  float ca = 0.0f;
  __syncthreads();
  for (int b = 0; b < BG; ++b) {
    if (j < ZA) {
      float acc = XZa[(size_t)b * ZA + j];
#pragma unroll
      for (int k = 0; k < HG; ++k) acc += wa2[k] * grp[b * HG + k];
#pragma unroll
      for (int k = 0; k < HA; ++k) acc += wha[k] * haL[k];
      za[j] = acc;
    }
    __syncthreads();
    if (j < HA) {
      float zi = za[j], zf = za[HA + j], zg = za[2 * HA + j], zo = za[3 * HA + j];
      ca = sigf(zf) * ca + sigf(zi) * tanh_(zg);
      float h = sigf(zo) * tanh_(ca);
      haL[j] = h;
      res[b * HA + j] = h;
    }
    __syncthreads();
  }
  if (j < BG) {
    float x0 = res[j * 4 + 0], x1 = res[j * 4 + 1];
    float x2 = res[j * 4 + 2], x3 = res[j * 4 + 3];
    float m = fmaxf(fmaxf(x0, x1), fmaxf(x2, x3));
    float e0 = __expf(x0 - m), e1 = __expf(x1 - m);
    float e2 = __expf(x2 - m), e3 = __expf(x3 - m);
    float s = e0 + e1 + e2 + e3;
    out[j * 4 + 0] = e0 / s;
    out[j * 4 + 1] = e1 / s;
    out[j * 4 + 2] = e2 / s;
    out[j * 4 + 3] = e3 / s;
  }
}

__global__ void k_zero(float* out) { out[threadIdx.x] = 0.0f; }

extern "C" void kernel_launch(void* const* d_in, const int* in_sizes, int n_in,
                              void* d_out, int out_size, void* d_ws, size_t ws_size,
                              hipStream_t stream) {
  const void* nodes = d_in[0];
  const void* gattr = d_in[1];
  const int* eidx  = (const int*)d_in[2];
  const int* nn    = (const int*)d_in[3];
  const int* ne    = (const int*)d_in[4];
  const int* bidx  = (const int*)d_in[5];
  const int* who   = (const int*)d_in[6];

  if (ws_size < (size_t)WS_FLOATS * 4) {
    k_zero<<<1, 256, 0, stream>>>((float*)d_out);
    return;
  }

  float* ws = (float*)d_ws;
  int* flagp = (int*)d_ws;
  float* cva = ws + CV;
  float* XZm = cva + O_XZM;
  float* XZu = cva + O_XZU;
  float* XZg = cva + O_XZG;
  float* XZa = cva + O_XZA;
  float* upd = cva + O_UPD;
  float* msg = XZm;  // overlay (delayed-store ordering; see k_chain comment)

  k_detect<<<1, 64, 0, stream>>>((const u32*)nodes, flagp);
  k_convert<<<(CONV_TOTAL + 255) / 256, 256, 0, stream>>>(
      nodes, gattr,
      d_in[7], d_in[8], d_in[9], d_in[10],
      d_in[11], d_in[12], d_in[13], d_in[14],
      d_in[15], d_in[16], d_in[17], d_in[18],
      d_in[19], d_in[20], d_in[21], d_in[22],
      flagp, cva);
  k_pre<<<NEDGE + NNODE + BG, 256, 0, stream>>>(cva, eidx, nn, ne, XZm, XZu, XZg);
  k_chain<NEDGE><<<1, 1024, 0, stream>>>(cva + O_WHM, XZm, msg);
  k_aggminproj<<<NNODE, 256, 0, stream>>>(cva, msg, eidx, XZu);
  k_chain<NNODE><<<1, 1024, 0, stream>>>(cva + O_WHU, XZu, upd);
  k_gproj<<<2 * BG, 256, 0, stream>>>(cva, upd, bidx, who, XZg, XZa);
  k_final<<<1, 256, 0, stream>>>(cva, XZg, XZa, (float*)d_out);
}

// Round 4
// 1419.521 us; speedup vs baseline: 1.0118x; 1.0118x over previous
//
#include <hip/hip_runtime.h>

typedef unsigned int u32;
typedef unsigned short u16;
typedef float f32x2 __attribute__((ext_vector_type(2)));

#define BG 64
#define NNODE 320
#define NEDGE 1280
#define TT 256
#define FN 64
#define FG 16
#define HM 128
#define HU 128
#define HG 64
#define HA 4
#define ZM 512
#define ZU 512
#define ZG 256
#define ZA 16
#define DM 144
#define DU 208
#define DG 144
#define DA 192

// ---- conversion-area layout (floats, relative to ws+64) ----
#define CV 64
#define O_NODES 0
#define O_GA    20480
#define O_WM    21504
#define O_WHM   95232
#define O_BM    160768
#define O_WU    161280
#define O_WHU   267776
#define O_BU    333312
#define O_WG    333824
#define O_WHG   370688
#define O_BG2   387072
#define O_WA    387328
#define O_WHA   390400
#define O_BA    390464
#define CONV_TOTAL 390480
#define O_XZM   390528
#define O_XZU   (O_XZM + NEDGE * ZM)
#define O_XZG   (O_XZU + NNODE * ZU)
#define O_XZA   (O_XZG + BG * ZG)
#define O_AGGR  (O_XZA + BG * ZA)
#define O_AGGB  (O_AGGR + NNODE * HM)
#define O_UPD   (O_AGGB + BG * HU)
#define WS_FLOATS (CV + O_UPD + NNODE * HU)

__device__ __forceinline__ float bf2f(u16 v) {
  return __uint_as_float(((u32)v) << 16);
}
__device__ __forceinline__ float rcp_(float x) { return __builtin_amdgcn_rcpf(x); }
__device__ __forceinline__ float sigf(float x) { return rcp_(1.0f + __expf(-x)); }
__device__ __forceinline__ float tanh_(float x) {
  float e = __expf(-2.0f * fabsf(x));
  float t = (1.0f - e) * rcp_(1.0f + e);
  return copysignf(t, x);
}
__device__ __forceinline__ float cvt(const void* p, int i, int flag) {
  return flag ? bf2f(((const u16*)p)[i]) : ((const float*)p)[i];
}

// DPP cross-lane move (pure VALU, no DS pipe). quad_perm encodings:
// 0xB1 = [1,0,3,2] (lane^1), 0x4E = [2,3,0,1] (lane^2), 0x1B = [3,2,1,0] (lane^3).
template <int CTRL>
__device__ __forceinline__ float dppmov(float s) {
  return __int_as_float(
      __builtin_amdgcn_update_dpp(0, __float_as_int(s), CTRL, 0xF, 0xF, true));
}

// Packed 2xfp32 FMA (gfx90a+): one issue slot for two MACs. "v" constraints
// force arch-VGPR operands (an f32x2 maps to an even-aligned VGPR pair).
// NOTE (round-4): PIN32 removed. Rounds 0-3 proved the weight tile lives in
// AGPRs regardless of pressure/budget (VGPR_Count 84/48/52); plain VALU
// cannot source AGPRs on gfx9xx, so one accvgpr_read per weight-use is
// structural. PIN32's "+v" fence forced those copies into a just-in-time
// burst feeding each pk (round-3: VALUBusy 0.28, 29% stall). Without the
// fence the scheduler hoists copies into the ds_read shadow.
#define PKFMA(acc, w, h) \
  asm("v_pk_fma_f32 %0, %1, %2, %0" : "+v"(acc) : "v"(w), "v"(h))

// lgkmcnt-only barrier: LDS ordering without the vmcnt(0) drain that
// __syncthreads() emits. Global ops here are fire-and-forget stores (consumed
// by later kernels; visible at dispatch end) and prefetch loads (compiler
// inserts vmcnt wait at first use). See k_chain ordering proof in comments.
#define BAR() asm volatile("s_waitcnt lgkmcnt(0)\n\ts_barrier" ::: "memory")

// ---------------------------------------------------------------------------
// K-1: runtime dtype detector (unchanged; fp32 was detected).
// ---------------------------------------------------------------------------
__global__ void k_detect(const u32* __restrict__ raw, int* __restrict__ flagp) {
  const int t = threadIdx.x;  // 64 threads (1 wave)
  int zlo = 0, hits = 0;
  for (int k = t; k < 256; k += 64) {
    u32 w = raw[k];
    if ((w & 0xFFFFu) == 0u) zlo++;
    u32 m = (w >> 8) & 0x7Fu;
    if (m >= 40u && m <= 70u) hits++;
  }
#pragma unroll
  for (int off = 32; off; off >>= 1) {
    zlo += __shfl_down(zlo, off, 64);
    hits += __shfl_down(hits, off, 64);
  }
  if (t == 0) *flagp = (zlo < 128 && hits >= 128) ? 1 : 0;
}

// ---------------------------------------------------------------------------
// K0: convert weights/biases (+ t=255 slices) to fp32 in workspace.
// ---------------------------------------------------------------------------
__global__ __launch_bounds__(256) void k_convert(
    const void* nodes, const void* gattr,
    const void* Wm, const void* Whm, const void* bm1, const void* bm2,
    const void* Wu, const void* Whu, const void* bu1, const void* bu2,
    const void* Wg, const void* Whg, const void* bg1, const void* bg2,
    const void* Wa, const void* Wha, const void* ba1, const void* ba2,
    const int* __restrict__ flagp, float* __restrict__ dst) {
  const int flag = *flagp;
  const int i = blockIdx.x * 256 + threadIdx.x;
  if (i >= CONV_TOTAL) return;
  float v;
  if (i < O_GA) {
    int n = i >> 6, f = i & 63;
    v = cvt(nodes, (n * TT + (TT - 1)) * FN + f, flag);
  } else if (i < O_WM) {
    int l = i - O_GA; int b = l >> 4, g = l & 15;
    v = cvt(gattr, (b * TT + (TT - 1)) * FG + g, flag);
  } else if (i < O_BM) {
    v = (i < O_WHM) ? cvt(Wm, i - O_WM, flag) : cvt(Whm, i - O_WHM, flag);
  } else if (i < O_WU) {
    int l = i - O_BM; v = cvt(bm1, l, flag) + cvt(bm2, l, flag);
  } else if (i < O_BU) {
    v = (i < O_WHU) ? cvt(Wu, i - O_WU, flag) : cvt(Whu, i - O_WHU, flag);
  } else if (i < O_WG) {
    int l = i - O_BU; v = cvt(bu1, l, flag) + cvt(bu2, l, flag);
  } else if (i < O_BG2) {
    v = (i < O_WHG) ? cvt(Wg, i - O_WG, flag) : cvt(Whg, i - O_WHG, flag);
  } else if (i < O_WA) {
    int l = i - O_BG2; v = cvt(bg1, l, flag) + cvt(bg2, l, flag);
  } else if (i < O_WHA) {
    v = cvt(Wa, i - O_WA, flag);
  } else if (i < O_BA) {
    v = cvt(Wha, i - O_WHA, flag);
  } else {
    int l = i - O_BA; v = cvt(ba1, l, flag) + cvt(ba2, l, flag);
  }
  dst[i] = v;
}

// ---------------------------------------------------------------------------
// K1: parallel precompute of input projections at t = T-1 (unchanged).
// ---------------------------------------------------------------------------
__global__ __launch_bounds__(256) void k_pre(
    const float* __restrict__ cva,
    const int* __restrict__ eidx, const int* __restrict__ num_nodes,
    const int* __restrict__ num_edges,
    float* __restrict__ XZm, float* __restrict__ XZu, float* __restrict__ XZg) {
  const int blk = blockIdx.x, tid = threadIdx.x;
  __shared__ float xv[FN];
  __shared__ float gav[FG];
  __shared__ int sgr;
  const float* nodes255 = cva + O_NODES;
  const float* ga255 = cva + O_GA;

  if (blk < NEDGE) {
    const int e = blk;
    if (tid == 0) {
      int g = 0, acc = 0;
      while (g < BG) { int c = num_edges[g]; if (e < acc + c) break; acc += c; ++g; }
      if (g >= BG) g = BG - 1;
      sgr = g;
    }
    const int srcn = eidx[e];  // faithful: src == tgt == edge_indices[0]
    if (tid < FN) xv[tid] = nodes255[srcn * FN + tid];
    __syncthreads();
    if (tid < FG) gav[tid] = ga255[sgr * FG + tid];
    __syncthreads();
    for (int j = tid; j < ZM; j += 256) {
      const float* wr = cva + O_WM + j * DM;
      float acc = cva[O_BM + j];
#pragma unroll
      for (int d = 0; d < FN; ++d) acc += (wr[d] + wr[FN + d]) * xv[d];
#pragma unroll
      for (int d = 0; d < FG; ++d) acc += wr[2 * FN + d] * gav[d];
      XZm[(size_t)e * ZM + j] = acc;
    }
  } else if (blk < NEDGE + NNODE) {
    const int n = blk - NEDGE;
    if (tid == 0) {
      int g = 0, acc = 0;
      while (g < BG) { int c = num_nodes[g]; if (n < acc + c) break; acc += c; ++g; }
      if (g >= BG) g = BG - 1;
      sgr = g;
    }
    if (tid < FN) xv[tid] = nodes255[n * FN + tid];
    __syncthreads();
    if (tid < FG) gav[tid] = ga255[sgr * FG + tid];
    __syncthreads();
    for (int j = tid; j < ZU; j += 256) {
      const float* wr = cva + O_WU + j * DU;
      float acc = cva[O_BU + j];
#pragma unroll
      for (int d = 0; d < FN; ++d) acc += wr[d] * xv[d];
#pragma unroll
      for (int d = 0; d < FG; ++d) acc += wr[FN + HM + d] * gav[d];
      XZu[(size_t)n * ZU + j] = acc;
    }
  } else {
    const int b = blk - NEDGE - NNODE;
    if (tid < FG) gav[tid] = ga255[b * FG + tid];
    __syncthreads();
    if (tid < ZG) {
      const float* wr = cva + O_WG + tid * DG;
      float acc = cva[O_BG2 + tid];
#pragma unroll
      for (int d = 0; d < FG; ++d) acc += wr[HU + d] * gav[d];
      XZg[(size_t)b * ZG + tid] = acc;
    }
  }
}

// ---------------------------------------------------------------------------
// K2/K4: LSTM chain. 1024 threads (16 waves), issue-count-minimized form.
//
// Layout: 8-lane group = {quad q, quad q^32}: kc = (lane&3)|((lane&32)>>3)
// selects a 16-float k-chunk of h; elem = wv*8 + ((lane>>2)&7). Each lane
// computes 4 gate-partials as 8 v_pk_fma_f32 per gate (32 pk total = 64
// MACs), then a 3-round REDUCE-SCATTER (^1, ^2 via quad_perm DPP; ^32 via
// shfl) leaves z[gate p = lane&3] one-per-lane. Each lane runs ONE unified
// nonlinearity; c/h assembled in p==0 lanes via 3 quad_perm gathers.
//
// h double-buffered in LDS: 8 chunks x 20 floats (16 + 4 pad); the 8
// distinct b128 read addresses cover all 32 banks exactly once.
// Ordering proof for overlay (k_msg: hout overlays XZ region):
//   store of step e-1's h at step e touches XZ floats [(e-1)*128,(e)*128)
//   i.e. XZ row (e-1)/4 <= e-1; every wave consumed that row's loads
//   (vmcnt-waited at its z compute) before passing barrier e-1; prefetch at
//   step e reads row e+1 > (e-1)/4. No in-flight load can see the store.
//   Unconditional prefetch of row STEPS reads one row past XZ: still inside
//   the workspace (XZu follows XZm, XZg follows XZu); value unused.
// ---------------------------------------------------------------------------
template <int STEPS>
__global__ __launch_bounds__(1024, 4) void k_chain(
    const float* __restrict__ Whh, const float* __restrict__ XZ,
    float* __restrict__ hout) {
  const int lane = threadIdx.x & 63;
  const int wv = threadIdx.x >> 6;               // wave 0..15
  const int p = lane & 3;                        // gate this lane finalizes
  const int kc = (lane & 3) | ((lane & 32) >> 3);  // k-chunk 0..7
  const int elem = wv * 8 + ((lane >> 2) & 7);   // element 0..127
  const bool islead = (p == 0) && (lane < 32);   // 1 lane per element
  __shared__ float hbuf[2][160];                 // 8 chunks x (16 + 4 pad)

  f32x2 w[32];  // Whh rows {pp*128+elem}, cols kc*16..+15, as 8 pairs/gate
#pragma unroll
  for (int pp = 0; pp < 4; ++pp) {
    const float4* wr =
        (const float4*)(Whh + (size_t)(pp * 128 + elem) * 128 + kc * 16);
#pragma unroll
    for (int q = 0; q < 4; ++q) {
      float4 t = wr[q];
      f32x2 lo, hi;
      lo.x = t.x; lo.y = t.y; hi.x = t.z; hi.y = t.w;
      w[pp * 8 + 2 * q] = lo;
      w[pp * 8 + 2 * q + 1] = hi;
    }
  }
  // per-lane nonlinearity constants: sigmoid(z)=rcp(1+exp2(-z*log2e));
  // tanh(z)=2*rcp(1+exp2(-2z*log2e))-1. Unified: fma(smul, rcp(1+exp2(z*kmul)), badd)
  const float LOG2E = 1.4426950408889634f;
  const float kmul = (p == 2) ? (-2.0f * LOG2E) : (-LOG2E);
  const float smul = (p == 2) ? 2.0f : 1.0f;
  const float badd = (p == 2) ? -1.0f : 0.0f;
  const float KT2 = -2.0f * LOG2E;  // for tanh(c)

  if (threadIdx.x < 160) hbuf[0][threadIdx.x] = 0.0f;
  float c = 0.0f;
  float hrelu_prev = 0.0f;
  float xz = XZ[p * 128 + elem];
  BAR();
  int cur = 0;
  for (int e = 0; e < STEPS; ++e) {
    // h chunk (16 floats) from LDS, conflict-free b128 broadcast
    f32x2 hv2[8];
    const float4* hb = (const float4*)&hbuf[cur][kc * 20];
#pragma unroll
    for (int q = 0; q < 4; ++q) {
      float4 t = hb[q];
      hv2[2 * q].x = t.x; hv2[2 * q].y = t.y;
      hv2[2 * q + 1].x = t.z; hv2[2 * q + 1].y = t.w;
    }
    // 4 packed fmac chains (1 per gate): 32 pk = 64 MACs
    f32x2 a0, a1, a2, a3;
    a0.x = 0.0f; a0.y = 0.0f; a1 = a0; a2 = a0; a3 = a0;
#pragma unroll
    for (int k = 0; k < 8; ++k) {
      PKFMA(a0, w[0 * 8 + k], hv2[k]);
      PKFMA(a1, w[1 * 8 + k], hv2[k]);
      PKFMA(a2, w[2 * 8 + k], hv2[k]);
      PKFMA(a3, w[3 * 8 + k], hv2[k]);
    }
    float pa0 = a0.x + a0.y, pa1 = a1.x + a1.y;
    float pa2 = a2.x + a2.y, pa3 = a3.x + a3.y;
    // reduce-scatter: after this, z holds gate (lane&3) of elem, summed
    // over the 8-lane group. Exchange pattern: send my DISCARDED value
    // (= partner's kept gate), receive partner's discarded (= my kept).
    const bool o0 = (lane & 1) != 0, o1 = (lane & 2) != 0;
    float u0 = o0 ? pa1 : pa0, d0 = o0 ? pa0 : pa1;
    float u1 = o0 ? pa3 : pa2, d1 = o0 ? pa2 : pa3;
    u0 += dppmov<0xB1>(d0);
    u1 += dppmov<0xB1>(d1);
    float uu = o1 ? u1 : u0, dd = o1 ? u0 : u1;
    uu += dppmov<0x4E>(dd);
    float z = uu + __shfl_xor(uu, 32, 64) + xz;
    // prefetch next step's xz (own gate only; vmcnt at next use)
    xz = XZ[(size_t)(e + 1) * 512 + p * 128 + elem];
    // unified per-lane gate nonlinearity
    float ex = __builtin_amdgcn_exp2f(z * kmul);
    float gq = __builtin_fmaf(smul, rcp_(1.0f + ex), badd);
    // assemble c,h in p==0 lanes (others compute garbage, never read)
    float gf = dppmov<0xB1>(gq);  // sigmoid(zf) from lane^1
    float gt = dppmov<0x4E>(gq);  // tanh(zg)    from lane^2
    float go = dppmov<0x1B>(gq);  // sigmoid(zo) from lane^3
    c = __builtin_fmaf(gf, c, gq * gt);
    float ec = __builtin_amdgcn_exp2f(c * KT2);
    float th = __builtin_fmaf(2.0f, rcp_(1.0f + ec), -1.0f);
    float h = go * th;
    if (islead) {
      hbuf[cur ^ 1][(elem >> 4) * 20 + (elem & 15)] = h;
      if (e > 0) hout[(size_t)(e - 1) * 128 + elem] = hrelu_prev;
      hrelu_prev = fmaxf(h, 0.0f);
    }
    BAR();
    cur ^= 1;
  }
  if (islead) hout[(size_t)(STEPS - 1) * 128 + elem] = hrelu_prev;
}

// ---------------------------------------------------------------------------
// K3: fused segment_min over edges + aggr projection (was k_aggmin+k_aggproj;
// aggr never leaves the block). Block n: phase 1 (threads 0..127) computes
// aggr[n][j] = min over edges with eidx==n; phase 2 (all 256) does
// XZu[n] += Wih_u[:,64:192] @ aggr.
// ---------------------------------------------------------------------------
__global__ __launch_bounds__(256) void k_aggminproj(
    const float* __restrict__ cva, const float* __restrict__ msg,
    const int* __restrict__ eidx, float* __restrict__ XZu) {
  const int n = blockIdx.x, tid = threadIdx.x;
  __shared__ float av[HM];
  if (tid < HM) {
    float m = __uint_as_float(0x7f800000u);  // +inf (segment_min identity)
    for (int e = 0; e < NEDGE; ++e) {
      if (eidx[e] == n) m = fminf(m, msg[(size_t)e * HM + tid]);
    }
    av[tid] = m;
  }
  __syncthreads();
  for (int j = tid; j < ZU; j += 256) {
    const float* wr = cva + O_WU + j * DU + FN;
    float acc = 0.0f;
#pragma unroll
    for (int k = 0; k < HM; ++k) acc += wr[k] * av[k];
    XZu[(size_t)n * ZU + j] += acc;
  }
}

// ---------------------------------------------------------------------------
// K5: fused (aggB computed in-block, never global).
// blocks [0,64): aggB[b] = segmin(upd) -> XZg[b] += Wih_g[:,0:128] @ aggB[b]
// blocks [64,128): chosen[b] -> XZa[b] = Wih_a[:,0:128] @ chosen[b] + biases
// ---------------------------------------------------------------------------
__global__ __launch_bounds__(256) void k_gproj(
    const float* __restrict__ cva, const float* __restrict__ upd,
    const int* __restrict__ bidx, const int* __restrict__ who,
    float* __restrict__ XZg, float* __restrict__ XZa) {
  const int blk = blockIdx.x, tid = threadIdx.x;
  __shared__ float buf[HU];
  __shared__ int satbw;
  if (blk < BG) {
    const int b = blk;
    if (tid < HU) {
      float m = __uint_as_float(0x7f800000u);
      for (int n = 0; n < NNODE; ++n) {
        if (bidx[n] == b) m = fminf(m, upd[(size_t)n * HU + tid]);
      }
      buf[tid] = m;
    }
    __syncthreads();
    if (tid < ZG) {
      const float* wr = cva + O_WG + tid * DG;
      float acc = 0.0f;
#pragma unroll
      for (int k = 0; k < HU; ++k) acc += wr[k] * buf[k];
      XZg[(size_t)b * ZG + tid] += acc;
    }
  } else {
    const int b = blk - BG;
    const int whoB = who[b];
    if (tid == 0) {
      int off = 0;
      for (int i = 0; i < NNODE; ++i) off += (bidx[i] < b) ? 1 : 0;
      const int adj = (whoB == 3) ? 2 : whoB;
      satbw = (b == 0) ? who[0] : (adj + off);
    }
    if (whoB == 3) {
      if (tid < HU) {
        float m = __uint_as_float(0x7f800000u);
        for (int n = 0; n < NNODE; ++n) {
          if (bidx[n] == b) m = fminf(m, upd[(size_t)n * HU + tid]);
        }
        buf[tid] = m;
      }
      __syncthreads();
    } else {
      __syncthreads();
      if (tid < HU) buf[tid] = upd[(size_t)satbw * HU + tid];
      __syncthreads();
    }
    if (tid < ZA) {
      const float* wr = cva + O_WA + tid * DA;
      float acc = cva[O_BA + tid];
#pragma unroll
      for (int k = 0; k < HU; ++k) acc += wr[k] * buf[k];
      XZa[(size_t)b * ZA + tid] = acc;
    }
  }
}

// ---------------------------------------------------------------------------
// K6: group LSTM chain (64 steps, H=64) + action chain + softmax + fp32 out.
// ---------------------------------------------------------------------------
__global__ __launch_bounds__(256, 2) void k_final(
    const float* __restrict__ cva, const float* __restrict__ XZg,
    const float* __restrict__ XZa, float* __restrict__ out) {
  const int j = threadIdx.x;
  __shared__ __align__(16) float hg[HG];
  __shared__ float zsg[ZG];
  __shared__ float grp[BG * HG];
  __shared__ float za[ZA];
  __shared__ float haL[HA];
  __shared__ float res[BG * HA];

  float wg[HG];
  {
    const float* wr = cva + O_WHG + j * HG;
#pragma unroll
    for (int k = 0; k < HG; ++k) wg[k] = wr[k];
  }
  if (j < HG) hg[j] = 0.0f;
  float cg = 0.0f;
  __syncthreads();
  for (int b = 0; b < BG; ++b) {
    float acc = XZg[(size_t)b * ZG + j];
#pragma unroll
    for (int k = 0; k < HG; ++k) acc += wg[k] * hg[k];
    zsg[j] = acc;
    __syncthreads();
    if (j < HG) {
      float zi = zsg[j], zf = zsg[HG + j], zg = zsg[2 * HG + j], zo = zsg[3 * HG + j];
      cg = sigf(zf) * cg + sigf(zi) * tanh_(zg);
      float h = sigf(zo) * tanh_(cg);
      hg[j] = h;
      grp[b * HG + j] = fmaxf(h, 0.0f);
    }
    __syncthreads();
  }

  float wa2[HG];
  float wha[HA];
  if (j < ZA) {
    const float* wr2 = cva + O_WA + j * DA + HU;
#pragma unroll
    for (int k = 0; k < HG; ++k) wa2[k] = wr2[k];
#pragma unroll
    for (int k = 0; k < HA; ++k) wha[k] = cva[O_WHA + j * HA + k];
  }
  if (j < HA) haL[j] = 0.0f;
  float ca = 0.0f;
  __syncthreads();
  for (int b = 0; b < BG; ++b) {
    if (j < ZA) {
      float acc = XZa[(size_t)b * ZA + j];
#pragma unroll
      for (int k = 0; k < HG; ++k) acc += wa2[k] * grp[b * HG + k];
#pragma unroll
      for (int k = 0; k < HA; ++k) acc += wha[k] * haL[k];
      za[j] = acc;
    }
    __syncthreads();
    if (j < HA) {
      float zi = za[j], zf = za[HA + j], zg = za[2 * HA + j], zo = za[3 * HA + j];
      ca = sigf(zf) * ca + sigf(zi) * tanh_(zg);
      float h = sigf(zo) * tanh_(ca);
      haL[j] = h;
      res[b * HA + j] = h;
    }
    __syncthreads();
  }
  if (j < BG) {
    float x0 = res[j * 4 + 0], x1 = res[j * 4 + 1];
    float x2 = res[j * 4 + 2], x3 = res[j * 4 + 3];
    float m = fmaxf(fmaxf(x0, x1), fmaxf(x2, x3));
    float e0 = __expf(x0 - m), e1 = __expf(x1 - m);
    float e2 = __expf(x2 - m), e3 = __expf(x3 - m);
    float s = e0 + e1 + e2 + e3;
    out[j * 4 + 0] = e0 / s;
    out[j * 4 + 1] = e1 / s;
    out[j * 4 + 2] = e2 / s;
    out[j * 4 + 3] = e3 / s;
  }
}

__global__ void k_zero(float* out) { out[threadIdx.x] = 0.0f; }

extern "C" void kernel_launch(void* const* d_in, const int* in_sizes, int n_in,
                              void* d_out, int out_size, void* d_ws, size_t ws_size,
                              hipStream_t stream) {
  const void* nodes = d_in[0];
  const void* gattr = d_in[1];
  const int* eidx  = (const int*)d_in[2];
  const int* nn    = (const int*)d_in[3];
  const int* ne    = (const int*)d_in[4];
  const int* bidx  = (const int*)d_in[5];
  const int* who   = (const int*)d_in[6];

  if (ws_size < (size_t)WS_FLOATS * 4) {
    k_zero<<<1, 256, 0, stream>>>((float*)d_out);
    return;
  }

  float* ws = (float*)d_ws;
  int* flagp = (int*)d_ws;
  float* cva = ws + CV;
  float* XZm = cva + O_XZM;
  float* XZu = cva + O_XZU;
  float* XZg = cva + O_XZG;
  float* XZa = cva + O_XZA;
  float* upd = cva + O_UPD;
  float* msg = XZm;  // overlay (delayed-store ordering; see k_chain comment)

  k_detect<<<1, 64, 0, stream>>>((const u32*)nodes, flagp);
  k_convert<<<(CONV_TOTAL + 255) / 256, 256, 0, stream>>>(
      nodes, gattr,
      d_in[7], d_in[8], d_in[9], d_in[10],
      d_in[11], d_in[12], d_in[13], d_in[14],
      d_in[15], d_in[16], d_in[17], d_in[18],
      d_in[19], d_in[20], d_in[21], d_in[22],
      flagp, cva);
  k_pre<<<NEDGE + NNODE + BG, 256, 0, stream>>>(cva, eidx, nn, ne, XZm, XZu, XZg);
  k_chain<NEDGE><<<1, 1024, 0, stream>>>(cva + O_WHM, XZm, msg);
  k_aggminproj<<<NNODE, 256, 0, stream>>>(cva, msg, eidx, XZu);
  k_chain<NNODE><<<1, 1024, 0, stream>>>(cva + O_WHU, XZu, upd);
  k_gproj<<<2 * BG, 256, 0, stream>>>(cva, upd, bidx, who, XZg, XZa);
  k_final<<<1, 256, 0, stream>>>(cva, XZg, XZa, (float*)d_out);
}

// Round 5
// 1340.325 us; speedup vs baseline: 1.0716x; 1.0591x over previous
//
#include <hip/hip_runtime.h>

typedef unsigned int u32;
typedef unsigned short u16;
typedef float f32x2 __attribute__((ext_vector_type(2)));

#define BG 64
#define NNODE 320
#define NEDGE 1280
#define TT 256
#define FN 64
#define FG 16
#define HM 128
#define HU 128
#define HG 64
#define HA 4
#define ZM 512
#define ZU 512
#define ZG 256
#define ZA 16
#define DM 144
#define DU 208
#define DG 144
#define DA 192

// ---- conversion-area layout (floats, relative to ws+64) ----
#define CV 64
#define O_NODES 0
#define O_GA    20480
#define O_WM    21504
#define O_WHM   95232
#define O_BM    160768
#define O_WU    161280
#define O_WHU   267776
#define O_BU    333312
#define O_WG    333824
#define O_WHG   370688
#define O_BG2   387072
#define O_WA    387328
#define O_WHA   390400
#define O_BA    390464
#define CONV_TOTAL 390480
#define O_XZM   390528
#define O_XZU   (O_XZM + NEDGE * ZM)
#define O_XZG   (O_XZU + NNODE * ZU)
#define O_XZA   (O_XZG + BG * ZG)
#define O_AGGR  (O_XZA + BG * ZA)
#define O_AGGB  (O_AGGR + NNODE * HM)
#define O_UPD   (O_AGGB + BG * HU)
#define WS_FLOATS (CV + O_UPD + NNODE * HU)

__device__ __forceinline__ float bf2f(u16 v) {
  return __uint_as_float(((u32)v) << 16);
}
__device__ __forceinline__ float rcp_(float x) { return __builtin_amdgcn_rcpf(x); }
__device__ __forceinline__ float sigf(float x) { return rcp_(1.0f + __expf(-x)); }
__device__ __forceinline__ float tanh_(float x) {
  float e = __expf(-2.0f * fabsf(x));
  float t = (1.0f - e) * rcp_(1.0f + e);
  return copysignf(t, x);
}
__device__ __forceinline__ float cvt(const void* p, int i, int flag) {
  return flag ? bf2f(((const u16*)p)[i]) : ((const float*)p)[i];
}

// DPP cross-lane move (pure VALU, no DS pipe). Encodings:
// 0xB1 = quad_perm[1,0,3,2] (lane^1), 0x4E = quad_perm[2,3,0,1] (lane^2),
// 0x1B = quad_perm[3,2,1,0] (lane^3), 0x141 = row_half_mirror (lane^7
// within each 8-lane half-row).
template <int CTRL>
__device__ __forceinline__ float dppmov(float s) {
  return __int_as_float(
      __builtin_amdgcn_update_dpp(0, __float_as_int(s), CTRL, 0xF, 0xF, true));
}

// Packed 2xfp32 FMA (gfx90a+): one issue slot for two MACs.
#define PKFMA(acc, w, h) \
  asm("v_pk_fma_f32 %0, %1, %2, %0" : "+v"(acc) : "v"(w), "v"(h))

// lgkmcnt-only barrier: LDS ordering without the vmcnt(0) drain that
// __syncthreads() emits. Global ops here are fire-and-forget stores (consumed
// by later kernels; visible at dispatch end) and prefetch loads (compiler
// inserts vmcnt wait at first use). See k_chain ordering proof in comments.
#define BAR() asm volatile("s_waitcnt lgkmcnt(0)\n\ts_barrier" ::: "memory")

// ---------------------------------------------------------------------------
// K-1: runtime dtype detector (unchanged; fp32 was detected).
// ---------------------------------------------------------------------------
__global__ void k_detect(const u32* __restrict__ raw, int* __restrict__ flagp) {
  const int t = threadIdx.x;  // 64 threads (1 wave)
  int zlo = 0, hits = 0;
  for (int k = t; k < 256; k += 64) {
    u32 w = raw[k];
    if ((w & 0xFFFFu) == 0u) zlo++;
    u32 m = (w >> 8) & 0x7Fu;
    if (m >= 40u && m <= 70u) hits++;
  }
#pragma unroll
  for (int off = 32; off; off >>= 1) {
    zlo += __shfl_down(zlo, off, 64);
    hits += __shfl_down(hits, off, 64);
  }
  if (t == 0) *flagp = (zlo < 128 && hits >= 128) ? 1 : 0;
}

// ---------------------------------------------------------------------------
// K0: convert weights/biases (+ t=255 slices) to fp32 in workspace.
// ---------------------------------------------------------------------------
__global__ __launch_bounds__(256) void k_convert(
    const void* nodes, const void* gattr,
    const void* Wm, const void* Whm, const void* bm1, const void* bm2,
    const void* Wu, const void* Whu, const void* bu1, const void* bu2,
    const void* Wg, const void* Whg, const void* bg1, const void* bg2,
    const void* Wa, const void* Wha, const void* ba1, const void* ba2,
    const int* __restrict__ flagp, float* __restrict__ dst) {
  const int flag = *flagp;
  const int i = blockIdx.x * 256 + threadIdx.x;
  if (i >= CONV_TOTAL) return;
  float v;
  if (i < O_GA) {
    int n = i >> 6, f = i & 63;
    v = cvt(nodes, (n * TT + (TT - 1)) * FN + f, flag);
  } else if (i < O_WM) {
    int l = i - O_GA; int b = l >> 4, g = l & 15;
    v = cvt(gattr, (b * TT + (TT - 1)) * FG + g, flag);
  } else if (i < O_BM) {
    v = (i < O_WHM) ? cvt(Wm, i - O_WM, flag) : cvt(Whm, i - O_WHM, flag);
  } else if (i < O_WU) {
    int l = i - O_BM; v = cvt(bm1, l, flag) + cvt(bm2, l, flag);
  } else if (i < O_BU) {
    v = (i < O_WHU) ? cvt(Wu, i - O_WU, flag) : cvt(Whu, i - O_WHU, flag);
  } else if (i < O_WG) {
    int l = i - O_BU; v = cvt(bu1, l, flag) + cvt(bu2, l, flag);
  } else if (i < O_BG2) {
    v = (i < O_WHG) ? cvt(Wg, i - O_WG, flag) : cvt(Whg, i - O_WHG, flag);
  } else if (i < O_WA) {
    int l = i - O_BG2; v = cvt(bg1, l, flag) + cvt(bg2, l, flag);
  } else if (i < O_WHA) {
    v = cvt(Wa, i - O_WA, flag);
  } else if (i < O_BA) {
    v = cvt(Wha, i - O_WHA, flag);
  } else {
    int l = i - O_BA; v = cvt(ba1, l, flag) + cvt(ba2, l, flag);
  }
  dst[i] = v;
}

// ---------------------------------------------------------------------------
// K1: parallel precompute of input projections at t = T-1 (unchanged).
// ---------------------------------------------------------------------------
__global__ __launch_bounds__(256) void k_pre(
    const float* __restrict__ cva,
    const int* __restrict__ eidx, const int* __restrict__ num_nodes,
    const int* __restrict__ num_edges,
    float* __restrict__ XZm, float* __restrict__ XZu, float* __restrict__ XZg) {
  const int blk = blockIdx.x, tid = threadIdx.x;
  __shared__ float xv[FN];
  __shared__ float gav[FG];
  __shared__ int sgr;
  const float* nodes255 = cva + O_NODES;
  const float* ga255 = cva + O_GA;

  if (blk < NEDGE) {
    const int e = blk;
    if (tid == 0) {
      int g = 0, acc = 0;
      while (g < BG) { int c = num_edges[g]; if (e < acc + c) break; acc += c; ++g; }
      if (g >= BG) g = BG - 1;
      sgr = g;
    }
    const int srcn = eidx[e];  // faithful: src == tgt == edge_indices[0]
    if (tid < FN) xv[tid] = nodes255[srcn * FN + tid];
    __syncthreads();
    if (tid < FG) gav[tid] = ga255[sgr * FG + tid];
    __syncthreads();
    for (int j = tid; j < ZM; j += 256) {
      const float* wr = cva + O_WM + j * DM;
      float acc = cva[O_BM + j];
#pragma unroll
      for (int d = 0; d < FN; ++d) acc += (wr[d] + wr[FN + d]) * xv[d];
#pragma unroll
      for (int d = 0; d < FG; ++d) acc += wr[2 * FN + d] * gav[d];
      XZm[(size_t)e * ZM + j] = acc;
    }
  } else if (blk < NEDGE + NNODE) {
    const int n = blk - NEDGE;
    if (tid == 0) {
      int g = 0, acc = 0;
      while (g < BG) { int c = num_nodes[g]; if (n < acc + c) break; acc += c; ++g; }
      if (g >= BG) g = BG - 1;
      sgr = g;
    }
    if (tid < FN) xv[tid] = nodes255[n * FN + tid];
    __syncthreads();
    if (tid < FG) gav[tid] = ga255[sgr * FG + tid];
    __syncthreads();
    for (int j = tid; j < ZU; j += 256) {
      const float* wr = cva + O_WU + j * DU;
      float acc = cva[O_BU + j];
#pragma unroll
      for (int d = 0; d < FN; ++d) acc += wr[d] * xv[d];
#pragma unroll
      for (int d = 0; d < FG; ++d) acc += wr[FN + HM + d] * gav[d];
      XZu[(size_t)n * ZU + j] = acc;
    }
  } else {
    const int b = blk - NEDGE - NNODE;
    if (tid < FG) gav[tid] = ga255[b * FG + tid];
    __syncthreads();
    if (tid < ZG) {
      const float* wr = cva + O_WG + tid * DG;
      float acc = cva[O_BG2 + tid];
#pragma unroll
      for (int d = 0; d < FG; ++d) acc += wr[HU + d] * gav[d];
      XZg[(size_t)b * ZG + tid] = acc;
    }
  }
}

// ---------------------------------------------------------------------------
// K2/K4: LSTM chain. 1024 threads (16 waves). DS-free cross-lane exchange.
//
// Round-5 change: 8-lane k-group is now 8 CONTIGUOUS lanes (two adjacent
// quads). The old {quad q, quad q+32} grouping needed a cross-32 hop =
// ds_bpermute (~100 cy DS-pipe latency + an lgkm wait), executed in lockstep
// by all 16 waves each step -> pure serial stall (rounds 3/4: VALUBusy 0.28,
// ~28% stall). Now the 3rd reduce round is row_half_mirror (lane^7), pure
// VALU DPP.
//   kc = lane&7 (k-chunk), grp = lane>>3, elem = wv*8+grp.
//   Gate mapping is XOR-flipped in odd quads: p = (lane&3) ^ 3*((lane>>2)&1).
//   Then lane i and i^7 own the SAME gate (p_{i^7} = ((i&3)^3)^3*(b2^1) =
//   p_i), so round 3 needs no selects; and the quad_perm gathers ^1,^2,^3
//   still deliver gates 1,2,3 relative to any p==0 lane under the flipped
//   mapping (gate of L^j = (L&3 ^ j) ^ 3*b2 = j when p_L = 0).
// Reduce-scatter rounds 1-2 keep gate-bit_j == lane-bit_j ^ b2 (sel0/sel1).
//
// h double-buffered in LDS: 8 chunks x 20 floats; chunk kc starts at float
// 20*kc -> banks {0,20,8,28,16,4,24,12}, each b128 spans 4 banks: all 32
// banks covered once, conflict-free.
// Ordering proof for overlay (k_msg: hout overlays XZ region):
//   store of step e-1's h at step e touches XZ floats [(e-1)*128,(e)*128)
//   i.e. XZ row (e-1)/4 <= e-1; every wave consumed that row's loads
//   (vmcnt-waited at its z compute) before passing barrier e-1; prefetch at
//   step e reads row e+1 > (e-1)/4. No in-flight load can see the store.
//   Unconditional prefetch of row STEPS reads one row past XZ: still inside
//   the workspace (XZu follows XZm, XZg follows XZu); value unused.
// ---------------------------------------------------------------------------
template <int STEPS>
__global__ __launch_bounds__(1024, 4) void k_chain(
    const float* __restrict__ Whh, const float* __restrict__ XZ,
    float* __restrict__ hout) {
  const int lane = threadIdx.x & 63;
  const int wv = threadIdx.x >> 6;            // wave 0..15
  const int kc = lane & 7;                    // k-chunk 0..7 (16 floats each)
  const int grp = lane >> 3;                  // group-in-wave 0..7
  const int elem = wv * 8 + grp;              // element 0..127
  const int b2 = (lane >> 2) & 1;             // odd-quad flag
  const int p = (lane & 3) ^ (3 * b2);        // gate this lane finalizes
  const bool islead = ((lane & 7) == 0);      // lane 8g+0: p==0, one per group
  __shared__ float hbuf[2][160];              // 8 chunks x (16 + 4 pad)

  f32x2 w[32];  // Whh rows {pp*128+elem}, cols kc*16..+15, as 8 pairs/gate
#pragma unroll
  for (int pp = 0; pp < 4; ++pp) {
    const float4* wr =
        (const float4*)(Whh + (size_t)(pp * 128 + elem) * 128 + kc * 16);
#pragma unroll
    for (int q = 0; q < 4; ++q) {
      float4 t = wr[q];
      f32x2 lo, hi;
      lo.x = t.x; lo.y = t.y; hi.x = t.z; hi.y = t.w;
      w[pp * 8 + 2 * q] = lo;
      w[pp * 8 + 2 * q + 1] = hi;
    }
  }
  // per-lane nonlinearity constants: sigmoid(z)=rcp(1+exp2(-z*log2e));
  // tanh(z)=2*rcp(1+exp2(-2z*log2e))-1. Unified: fma(smul, rcp(1+exp2(z*kmul)), badd)
  const float LOG2E = 1.4426950408889634f;
  const float kmul = (p == 2) ? (-2.0f * LOG2E) : (-LOG2E);
  const float smul = (p == 2) ? 2.0f : 1.0f;
  const float badd = (p == 2) ? -1.0f : 0.0f;
  const float KT2 = -2.0f * LOG2E;  // for tanh(c)

  if (threadIdx.x < 160) hbuf[0][threadIdx.x] = 0.0f;
  float c = 0.0f;
  float hrelu_prev = 0.0f;
  float xz = XZ[p * 128 + elem];
  BAR();
  int cur = 0;
  for (int e = 0; e < STEPS; ++e) {
    // h chunk (16 floats) from LDS, conflict-free b128 broadcast
    f32x2 hv2[8];
    const float4* hb = (const float4*)&hbuf[cur][kc * 20];
#pragma unroll
    for (int q = 0; q < 4; ++q) {
      float4 t = hb[q];
      hv2[2 * q].x = t.x; hv2[2 * q].y = t.y;
      hv2[2 * q + 1].x = t.z; hv2[2 * q + 1].y = t.w;
    }
    // 4 packed fmac chains (1 per gate): 32 pk = 64 MACs
    f32x2 a0, a1, a2, a3;
    a0.x = 0.0f; a0.y = 0.0f; a1 = a0; a2 = a0; a3 = a0;
#pragma unroll
    for (int k = 0; k < 8; ++k) {
      PKFMA(a0, w[0 * 8 + k], hv2[k]);
      PKFMA(a1, w[1 * 8 + k], hv2[k]);
      PKFMA(a2, w[2 * 8 + k], hv2[k]);
      PKFMA(a3, w[3 * 8 + k], hv2[k]);
    }
    float pa0 = a0.x + a0.y, pa1 = a1.x + a1.y;
    float pa2 = a2.x + a2.y, pa3 = a3.x + a3.y;
    // reduce-scatter, all-DPP: keep gate-bit_j == lane-bit_j ^ b2.
    // Round 1 (^1) and 2 (^2) are quad_perm; round 3 (^7, same gate on
    // both sides under the flipped mapping) is row_half_mirror.
    const int sel0 = (lane & 1) ^ b2;
    const int sel1 = ((lane >> 1) & 1) ^ b2;
    float u0 = sel0 ? pa1 : pa0, d0 = sel0 ? pa0 : pa1;
    float u1 = sel0 ? pa3 : pa2, d1 = sel0 ? pa2 : pa3;
    u0 += dppmov<0xB1>(d0);
    u1 += dppmov<0xB1>(d1);
    float uu = sel1 ? u1 : u0, dd = sel1 ? u0 : u1;
    uu += dppmov<0x4E>(dd);
    uu += dppmov<0x141>(uu);  // lane^7: other quad, same gate
    float z = uu + xz;
    // prefetch next step's xz (own gate only; vmcnt at next use)
    xz = XZ[(size_t)(e + 1) * 512 + p * 128 + elem];
    // unified per-lane gate nonlinearity
    float ex = __builtin_amdgcn_exp2f(z * kmul);
    float gq = __builtin_fmaf(smul, rcp_(1.0f + ex), badd);
    // assemble c,h (valid in p==0 lanes; others compute garbage, never read)
    float gf = dppmov<0xB1>(gq);  // sigmoid(zf) from lane^1
    float gt = dppmov<0x4E>(gq);  // tanh(zg)    from lane^2
    float go = dppmov<0x1B>(gq);  // sigmoid(zo) from lane^3
    c = __builtin_fmaf(gf, c, gq * gt);
    float ec = __builtin_amdgcn_exp2f(c * KT2);
    float th = __builtin_fmaf(2.0f, rcp_(1.0f + ec), -1.0f);
    float h = go * th;
    if (islead) {
      hbuf[cur ^ 1][(elem >> 4) * 20 + (elem & 15)] = h;
      if (e > 0) hout[(size_t)(e - 1) * 128 + elem] = hrelu_prev;
      hrelu_prev = fmaxf(h, 0.0f);
    }
    BAR();
    cur ^= 1;
  }
  if (islead) hout[(size_t)(STEPS - 1) * 128 + elem] = hrelu_prev;
}

// ---------------------------------------------------------------------------
// K3: fused segment_min over edges + aggr projection (aggr never leaves the
// block). Block n: phase 1 (threads 0..127) computes aggr[n][j] = min over
// edges with eidx==n; phase 2 (all 256) does XZu[n] += Wih_u[:,64:192]@aggr.
// ---------------------------------------------------------------------------
__global__ __launch_bounds__(256) void k_aggminproj(
    const float* __restrict__ cva, const float* __restrict__ msg,
    const int* __restrict__ eidx, float* __restrict__ XZu) {
  const int n = blockIdx.x, tid = threadIdx.x;
  __shared__ float av[HM];
  if (tid < HM) {
    float m = __uint_as_float(0x7f800000u);  // +inf (segment_min identity)
    for (int e = 0; e < NEDGE; ++e) {
      if (eidx[e] == n) m = fminf(m, msg[(size_t)e * HM + tid]);
    }
    av[tid] = m;
  }
  __syncthreads();
  for (int j = tid; j < ZU; j += 256) {
    const float* wr = cva + O_WU + j * DU + FN;
    float acc = 0.0f;
#pragma unroll
    for (int k = 0; k < HM; ++k) acc += wr[k] * av[k];
    XZu[(size_t)n * ZU + j] += acc;
  }
}

// ---------------------------------------------------------------------------
// K5: fused (aggB computed in-block, never global).
// blocks [0,64): aggB[b] = segmin(upd) -> XZg[b] += Wih_g[:,0:128] @ aggB[b]
// blocks [64,128): chosen[b] -> XZa[b] = Wih_a[:,0:128] @ chosen[b] + biases
// ---------------------------------------------------------------------------
__global__ __launch_bounds__(256) void k_gproj(
    const float* __restrict__ cva, const float* __restrict__ upd,
    const int* __restrict__ bidx, const int* __restrict__ who,
    float* __restrict__ XZg, float* __restrict__ XZa) {
  const int blk = blockIdx.x, tid = threadIdx.x;
  __shared__ float buf[HU];
  __shared__ int satbw;
  if (blk < BG) {
    const int b = blk;
    if (tid < HU) {
      float m = __uint_as_float(0x7f800000u);
      for (int n = 0; n < NNODE; ++n) {
        if (bidx[n] == b) m = fminf(m, upd[(size_t)n * HU + tid]);
      }
      buf[tid] = m;
    }
    __syncthreads();
    if (tid < ZG) {
      const float* wr = cva + O_WG + tid * DG;
      float acc = 0.0f;
#pragma unroll
      for (int k = 0; k < HU; ++k) acc += wr[k] * buf[k];
      XZg[(size_t)b * ZG + tid] += acc;
    }
  } else {
    const int b = blk - BG;
    const int whoB = who[b];
    if (tid == 0) {
      int off = 0;
      for (int i = 0; i < NNODE; ++i) off += (bidx[i] < b) ? 1 : 0;
      const int adj = (whoB == 3) ? 2 : whoB;
      satbw = (b == 0) ? who[0] : (adj + off);
    }
    if (whoB == 3) {
      if (tid < HU) {
        float m = __uint_as_float(0x7f800000u);
        for (int n = 0; n < NNODE; ++n) {
          if (bidx[n] == b) m = fminf(m, upd[(size_t)n * HU + tid]);
        }
        buf[tid] = m;
      }
      __syncthreads();
    } else {
      __syncthreads();
      if (tid < HU) buf[tid] = upd[(size_t)satbw * HU + tid];
      __syncthreads();
    }
    if (tid < ZA) {
      const float* wr = cva + O_WA + tid * DA;
      float acc = cva[O_BA + tid];
#pragma unroll
      for (int k = 0; k < HU; ++k) acc += wr[k] * buf[k];
      XZa[(size_t)b * ZA + tid] = acc;
    }
  }
}

// ---------------------------------------------------------------------------
// K6: group LSTM chain (64 steps, H=64) + action chain + softmax + fp32 out.
// ---------------------------------------------------------------------------
__global__ __launch_bounds__(256, 2) void k_final(
    const float* __restrict__ cva, const float* __restrict__ XZg,
    const float* __restrict__ XZa, float* __restrict__ out) {
  const int j = threadIdx.x;
  __shared__ __align__(16) float hg[HG];
  __shared__ float zsg[ZG];
  __shared__ float grp[BG * HG];
  __shared__ float za[ZA];
  __shared__ float haL[HA];
  __shared__ float res[BG * HA];

  float wg[HG];
  {
    const float* wr = cva + O_WHG + j * HG;
#pragma unroll
    for (int k = 0; k < HG; ++k) wg[k] = wr[k];
  }
  if (j < HG) hg[j] = 0.0f;
  float cg = 0.0f;
  __syncthreads();
  for (int b = 0; b < BG; ++b) {
    float acc = XZg[(size_t)b * ZG + j];
#pragma unroll
    for (int k = 0; k < HG; ++k) acc += wg[k] * hg[k];
    zsg[j] = acc;
    __syncthreads();
    if (j < HG) {
      float zi = zsg[j], zf = zsg[HG + j], zg = zsg[2 * HG + j], zo = zsg[3 * HG + j];
      cg = sigf(zf) * cg + sigf(zi) * tanh_(zg);
      float h = sigf(zo) * tanh_(cg);
      hg[j] = h;
      grp[b * HG + j] = fmaxf(h, 0.0f);
    }
    __syncthreads();
  }

  float wa2[HG];
  float wha[HA];
  if (j < ZA) {
    const float* wr2 = cva + O_WA + j * DA + HU;
#pragma unroll
    for (int k = 0; k < HG; ++k) wa2[k] = wr2[k];
#pragma unroll
    for (int k = 0; k < HA; ++k) wha[k] = cva[O_WHA + j * HA + k];
  }
  if (j < HA) haL[j] = 0.0f;
  float ca = 0.0f;
  __syncthreads();
  for (int b = 0; b < BG; ++b) {
    if (j < ZA) {
      float acc = XZa[(size_t)b * ZA + j];
#pragma unroll
      for (int k = 0; k < HG; ++k) acc += wa2[k] * grp[b * HG + k];
#pragma unroll
      for (int k = 0; k < HA; ++k) acc += wha[k] * haL[k];
      za[j] = acc;
    }
    __syncthreads();
    if (j < HA) {
      float zi = za[j], zf = za[HA + j], zg = za[2 * HA + j], zo = za[3 * HA + j];
      ca = sigf(zf) * ca + sigf(zi) * tanh_(zg);
      float h = sigf(zo) * tanh_(ca);
      haL[j] = h;
      res[b * HA + j] = h;
    }
    __syncthreads();
  }
  if (j < BG) {
    float x0 = res[j * 4 + 0], x1 = res[j * 4 + 1];
    float x2 = res[j * 4 + 2], x3 = res[j * 4 + 3];
    float m = fmaxf(fmaxf(x0, x1), fmaxf(x2, x3));
    float e0 = __expf(x0 - m), e1 = __expf(x1 - m);
    float e2 = __expf(x2 - m), e3 = __expf(x3 - m);
    float s = e0 + e1 + e2 + e3;
    out[j * 4 + 0] = e0 / s;
    out[j * 4 + 1] = e1 / s;
    out[j * 4 + 2] = e2 / s;
    out[j * 4 + 3] = e3 / s;
  }
}

__global__ void k_zero(float* out) { out[threadIdx.x] = 0.0f; }

extern "C" void kernel_launch(void* const* d_in, const int* in_sizes, int n_in,
                              void* d_out, int out_size, void* d_ws, size_t ws_size,
                              hipStream_t stream) {
  const void* nodes = d_in[0];
  const void* gattr = d_in[1];
  const int* eidx  = (const int*)d_in[2];
  const int* nn    = (const int*)d_in[3];
  const int* ne    = (const int*)d_in[4];
  const int* bidx  = (const int*)d_in[5];
  const int* who   = (const int*)d_in[6];

  if (ws_size < (size_t)WS_FLOATS * 4) {
    k_zero<<<1, 256, 0, stream>>>((float*)d_out);
    return;
  }

  float* ws = (float*)d_ws;
  int* flagp = (int*)d_ws;
  float* cva = ws + CV;
  float* XZm = cva + O_XZM;
  float* XZu = cva + O_XZU;
  float* XZg = cva + O_XZG;
  float* XZa = cva + O_XZA;
  float* upd = cva + O_UPD;
  float* msg = XZm;  // overlay (delayed-store ordering; see k_chain comment)

  k_detect<<<1, 64, 0, stream>>>((const u32*)nodes, flagp);
  k_convert<<<(CONV_TOTAL + 255) / 256, 256, 0, stream>>>(
      nodes, gattr,
      d_in[7], d_in[8], d_in[9], d_in[10],
      d_in[11], d_in[12], d_in[13], d_in[14],
      d_in[15], d_in[16], d_in[17], d_in[18],
      d_in[19], d_in[20], d_in[21], d_in[22],
      flagp, cva);
  k_pre<<<NEDGE + NNODE + BG, 256, 0, stream>>>(cva, eidx, nn, ne, XZm, XZu, XZg);
  k_chain<NEDGE><<<1, 1024, 0, stream>>>(cva + O_WHM, XZm, msg);
  k_aggminproj<<<NNODE, 256, 0, stream>>>(cva, msg, eidx, XZu);
  k_chain<NNODE><<<1, 1024, 0, stream>>>(cva + O_WHU, XZu, upd);
  k_gproj<<<2 * BG, 256, 0, stream>>>(cva, upd, bidx, who, XZg, XZa);
  k_final<<<1, 256, 0, stream>>>(cva, XZg, XZa, (float*)d_out);
}

// Round 7
// 1299.070 us; speedup vs baseline: 1.1056x; 1.0318x over previous
//
#include <hip/hip_runtime.h>

typedef unsigned int u32;
typedef unsigned short u16;
typedef float f32x2 __attribute__((ext_vector_type(2)));

#define BG 64
#define NNODE 320
#define NEDGE 1280
#define TT 256
#define FN 64
#define FG 16
#define HM 128
#define HU 128
#define HG 64
#define HA 4
#define ZM 512
#define ZU 512
#define ZG 256
#define ZA 16
#define DM 144
#define DU 208
#define DG 144
#define DA 192

// ---- conversion-area layout (floats, relative to ws+64) ----
#define CV 64
#define O_NODES 0
#define O_GA    20480
#define O_WM    21504
#define O_WHM   95232
#define O_BM    160768
#define O_WU    161280
#define O_WHU   267776
#define O_BU    333312
#define O_WG    333824
#define O_WHG   370688
#define O_BG2   387072
#define O_WA    387328
#define O_WHA   390400
#define O_BA    390464
#define CONV_TOTAL 390480
#define O_XZM   390528
#define O_XZU   (O_XZM + NEDGE * ZM)
#define O_XZG   (O_XZU + NNODE * ZU)
#define O_XZA   (O_XZG + BG * ZG)
#define O_AGGR  (O_XZA + BG * ZA)
#define O_AGGB  (O_AGGR + NNODE * HM)
#define O_UPD   (O_AGGB + BG * HU)
#define WS_FLOATS (CV + O_UPD + NNODE * HU)

__device__ __forceinline__ float bf2f(u16 v) {
  return __uint_as_float(((u32)v) << 16);
}
__device__ __forceinline__ float rcp_(float x) { return __builtin_amdgcn_rcpf(x); }
__device__ __forceinline__ float sigf(float x) { return rcp_(1.0f + __expf(-x)); }
__device__ __forceinline__ float tanh_(float x) {
  float e = __expf(-2.0f * fabsf(x));
  float t = (1.0f - e) * rcp_(1.0f + e);
  return copysignf(t, x);
}
__device__ __forceinline__ float cvt(const void* p, int i, int flag) {
  return flag ? bf2f(((const u16*)p)[i]) : ((const float*)p)[i];
}

// pack 2 fp32 -> 2 fp16 in one u32 (v_cvt_pkrtz_f16_f32, RTZ; bias ~2^-12 rel)
// NOTE: builtin returns __fp16 ext_vector(2); take by auto + bit-copy (no-op).
__device__ __forceinline__ u32 pkrtz(float a, float b) {
  auto r = __builtin_amdgcn_cvt_pkrtz(a, b);
  u32 out;
  __builtin_memcpy(&out, &r, 4);
  return out;
}

// DPP cross-lane move (pure VALU, no DS pipe). Encodings:
// 0xB1 = quad_perm[1,0,3,2] (lane^1), 0x4E = quad_perm[2,3,0,1] (lane^2),
// 0x1B = quad_perm[3,2,1,0] (lane^3), 0x141 = row_half_mirror (lane^7
// within each 8-lane half-row).
template <int CTRL>
__device__ __forceinline__ float dppmov(float s) {
  return __int_as_float(
      __builtin_amdgcn_update_dpp(0, __float_as_int(s), CTRL, 0xF, 0xF, true));
}

// fp16 dot2 with fp32 accumulate (VOP3P): D = a.h0*b.h0 + a.h1*b.h1 + D.
// One issue slot for two MACs, scalar fp32 result (no horizontal add), and
// half the weight register footprint vs f32x2 pairs -> the 64-float tile
// becomes 32 VGPRs, fitting the 128-reg arch budget at 4 waves/SIMD (rounds
// 0-5: fp32 tile was AGPR-demoted at every shape -> 1 copy per MAC use).
#define DOT2(acc, w, h) \
  asm("v_dot2_f32_f16 %0, %1, %2, %0" : "+v"(acc) : "v"(w), "v"(h))

// lgkmcnt-only barrier: LDS ordering without the vmcnt(0) drain that
// __syncthreads() emits. Global ops here are fire-and-forget stores (consumed
// by later kernels; visible at dispatch end) and prefetch loads (compiler
// inserts vmcnt wait at first use). See k_chain ordering proof in comments.
#define BAR() asm volatile("s_waitcnt lgkmcnt(0)\n\ts_barrier" ::: "memory")

// ---------------------------------------------------------------------------
// K-1: runtime dtype detector (unchanged; fp32 was detected).
// ---------------------------------------------------------------------------
__global__ void k_detect(const u32* __restrict__ raw, int* __restrict__ flagp) {
  const int t = threadIdx.x;  // 64 threads (1 wave)
  int zlo = 0, hits = 0;
  for (int k = t; k < 256; k += 64) {
    u32 w = raw[k];
    if ((w & 0xFFFFu) == 0u) zlo++;
    u32 m = (w >> 8) & 0x7Fu;
    if (m >= 40u && m <= 70u) hits++;
  }
#pragma unroll
  for (int off = 32; off; off >>= 1) {
    zlo += __shfl_down(zlo, off, 64);
    hits += __shfl_down(hits, off, 64);
  }
  if (t == 0) *flagp = (zlo < 128 && hits >= 128) ? 1 : 0;
}

// ---------------------------------------------------------------------------
// K0: convert weights/biases (+ t=255 slices) to fp32 in workspace.
// ---------------------------------------------------------------------------
__global__ __launch_bounds__(256) void k_convert(
    const void* nodes, const void* gattr,
    const void* Wm, const void* Whm, const void* bm1, const void* bm2,
    const void* Wu, const void* Whu, const void* bu1, const void* bu2,
    const void* Wg, const void* Whg, const void* bg1, const void* bg2,
    const void* Wa, const void* Wha, const void* ba1, const void* ba2,
    const int* __restrict__ flagp, float* __restrict__ dst) {
  const int flag = *flagp;
  const int i = blockIdx.x * 256 + threadIdx.x;
  if (i >= CONV_TOTAL) return;
  float v;
  if (i < O_GA) {
    int n = i >> 6, f = i & 63;
    v = cvt(nodes, (n * TT + (TT - 1)) * FN + f, flag);
  } else if (i < O_WM) {
    int l = i - O_GA; int b = l >> 4, g = l & 15;
    v = cvt(gattr, (b * TT + (TT - 1)) * FG + g, flag);
  } else if (i < O_BM) {
    v = (i < O_WHM) ? cvt(Wm, i - O_WM, flag) : cvt(Whm, i - O_WHM, flag);
  } else if (i < O_WU) {
    int l = i - O_BM; v = cvt(bm1, l, flag) + cvt(bm2, l, flag);
  } else if (i < O_BU) {
    v = (i < O_WHU) ? cvt(Wu, i - O_WU, flag) : cvt(Whu, i - O_WHU, flag);
  } else if (i < O_WG) {
    int l = i - O_BU; v = cvt(bu1, l, flag) + cvt(bu2, l, flag);
  } else if (i < O_BG2) {
    v = (i < O_WHG) ? cvt(Wg, i - O_WG, flag) : cvt(Whg, i - O_WHG, flag);
  } else if (i < O_WA) {
    int l = i - O_BG2; v = cvt(bg1, l, flag) + cvt(bg2, l, flag);
  } else if (i < O_WHA) {
    v = cvt(Wa, i - O_WA, flag);
  } else if (i < O_BA) {
    v = cvt(Wha, i - O_WHA, flag);
  } else {
    int l = i - O_BA; v = cvt(ba1, l, flag) + cvt(ba2, l, flag);
  }
  dst[i] = v;
}

// ---------------------------------------------------------------------------
// K1: parallel precompute of input projections at t = T-1 (unchanged).
// ---------------------------------------------------------------------------
__global__ __launch_bounds__(256) void k_pre(
    const float* __restrict__ cva,
    const int* __restrict__ eidx, const int* __restrict__ num_nodes,
    const int* __restrict__ num_edges,
    float* __restrict__ XZm, float* __restrict__ XZu, float* __restrict__ XZg) {
  const int blk = blockIdx.x, tid = threadIdx.x;
  __shared__ float xv[FN];
  __shared__ float gav[FG];
  __shared__ int sgr;
  const float* nodes255 = cva + O_NODES;
  const float* ga255 = cva + O_GA;

  if (blk < NEDGE) {
    const int e = blk;
    if (tid == 0) {
      int g = 0, acc = 0;
      while (g < BG) { int c = num_edges[g]; if (e < acc + c) break; acc += c; ++g; }
      if (g >= BG) g = BG - 1;
      sgr = g;
    }
    const int srcn = eidx[e];  // faithful: src == tgt == edge_indices[0]
    if (tid < FN) xv[tid] = nodes255[srcn * FN + tid];
    __syncthreads();
    if (tid < FG) gav[tid] = ga255[sgr * FG + tid];
    __syncthreads();
    for (int j = tid; j < ZM; j += 256) {
      const float* wr = cva + O_WM + j * DM;
      float acc = cva[O_BM + j];
#pragma unroll
      for (int d = 0; d < FN; ++d) acc += (wr[d] + wr[FN + d]) * xv[d];
#pragma unroll
      for (int d = 0; d < FG; ++d) acc += wr[2 * FN + d] * gav[d];
      XZm[(size_t)e * ZM + j] = acc;
    }
  } else if (blk < NEDGE + NNODE) {
    const int n = blk - NEDGE;
    if (tid == 0) {
      int g = 0, acc = 0;
      while (g < BG) { int c = num_nodes[g]; if (n < acc + c) break; acc += c; ++g; }
      if (g >= BG) g = BG - 1;
      sgr = g;
    }
    if (tid < FN) xv[tid] = nodes255[n * FN + tid];
    __syncthreads();
    if (tid < FG) gav[tid] = ga255[sgr * FG + tid];
    __syncthreads();
    for (int j = tid; j < ZU; j += 256) {
      const float* wr = cva + O_WU + j * DU;
      float acc = cva[O_BU + j];
#pragma unroll
      for (int d = 0; d < FN; ++d) acc += wr[d] * xv[d];
#pragma unroll
      for (int d = 0; d < FG; ++d) acc += wr[FN + HM + d] * gav[d];
      XZu[(size_t)n * ZU + j] = acc;
    }
  } else {
    const int b = blk - NEDGE - NNODE;
    if (tid < FG) gav[tid] = ga255[b * FG + tid];
    __syncthreads();
    if (tid < ZG) {
      const float* wr = cva + O_WG + tid * DG;
      float acc = cva[O_BG2 + tid];
#pragma unroll
      for (int d = 0; d < FG; ++d) acc += wr[HU + d] * gav[d];
      XZg[(size_t)b * ZG + tid] = acc;
    }
  }
}

// ---------------------------------------------------------------------------
// K2/K4: LSTM chain. 1024 threads (16 waves). fp16-dot2 MAC core.
//
// 8-lane k-group = 8 contiguous lanes (round-5 layout, all-DPP exchange):
//   kc = lane&7 (k-chunk of 16 h), grp = lane>>3, elem = wv*8+grp.
//   Gate mapping XOR-flipped in odd quads: p = (lane&3) ^ 3*((lane>>2)&1);
//   lane i and i^7 own the same gate -> reduce round 3 = row_half_mirror.
// MAC: weights as 32 packed-fp16 u32 (w16), h read from LDS as packed-fp16
// pairs; 32 v_dot2_f32_f16 per lane = 64 MACs, fp32 accumulate, no
// horizontal adds. xz (input projection) stays exact fp32; only the
// recurrent term carries fp16 rounding (~1e-3 abs on z).
//
// h buffer: fp16, double-buffered, 8 chunks x 12 u32 (8 data + 4 pad).
// Chunk kc at u32 offset kc*12: 16B-aligned (b128-legal), banks
// {0,12,24,4,16,28,8,20} distinct; second b128 at +4 likewise. Lead lanes
// write their single h as u16 at halfword index (elem>>4)*24 + (elem&15).
//
// Ordering proof for overlay (k_msg: hout overlays XZ region):
//   store of step e-1's h at step e touches XZ floats [(e-1)*128,(e)*128)
//   i.e. XZ row (e-1)/4 <= e-1; every wave consumed that row's loads
//   (vmcnt-waited at its z compute) before passing barrier e-1; prefetch at
//   step e reads row e+1 > (e-1)/4. No in-flight load can see the store.
//   Unconditional prefetch of row STEPS reads one row past XZ: still inside
//   the workspace (XZu follows XZm, XZg follows XZu); value unused.
// ---------------------------------------------------------------------------
template <int STEPS>
__global__ __launch_bounds__(1024, 4) void k_chain(
    const float* __restrict__ Whh, const float* __restrict__ XZ,
    float* __restrict__ hout) {
  const int lane = threadIdx.x & 63;
  const int wv = threadIdx.x >> 6;            // wave 0..15
  const int kc = lane & 7;                    // k-chunk 0..7 (16 h each)
  const int grp = lane >> 3;                  // group-in-wave 0..7
  const int elem = wv * 8 + grp;              // element 0..127
  const int b2 = (lane >> 2) & 1;             // odd-quad flag
  const int p = (lane & 3) ^ (3 * b2);        // gate this lane finalizes
  const bool islead = ((lane & 7) == 0);      // lane 8g+0: p==0, one per group
  __shared__ u32 hbuf[2][96];                 // fp16 h: 8 chunks x (8+4) u32

  u32 w16[32];  // Whh rows {pp*128+elem}, cols kc*16..+15, packed fp16 pairs
#pragma unroll
  for (int pp = 0; pp < 4; ++pp) {
    const float4* wr =
        (const float4*)(Whh + (size_t)(pp * 128 + elem) * 128 + kc * 16);
#pragma unroll
    for (int q = 0; q < 4; ++q) {
      float4 t = wr[q];
      w16[pp * 8 + 2 * q] = pkrtz(t.x, t.y);
      w16[pp * 8 + 2 * q + 1] = pkrtz(t.z, t.w);
    }
  }
  // per-lane nonlinearity constants: sigmoid(z)=rcp(1+exp2(-z*log2e));
  // tanh(z)=2*rcp(1+exp2(-2z*log2e))-1. Unified: fma(smul, rcp(1+exp2(z*kmul)), badd)
  const float LOG2E = 1.4426950408889634f;
  const float kmul = (p == 2) ? (-2.0f * LOG2E) : (-LOG2E);
  const float smul = (p == 2) ? 2.0f : 1.0f;
  const float badd = (p == 2) ? -1.0f : 0.0f;
  const float KT2 = -2.0f * LOG2E;  // for tanh(c)

  if (threadIdx.x < 192) ((u32*)hbuf)[threadIdx.x] = 0u;  // h=0 (fp16 zero)
  float c = 0.0f;
  float hrelu_prev = 0.0f;
  float xz = XZ[p * 128 + elem];
  BAR();
  int cur = 0;
  for (int e = 0; e < STEPS; ++e) {
    // h chunk (16 fp16 = 8 u32) from LDS, two b128, conflict-free broadcast
    const uint4* hb = (const uint4*)&hbuf[cur][kc * 12];
    uint4 ta = hb[0], tb = hb[1];
    u32 hv[8] = {ta.x, ta.y, ta.z, ta.w, tb.x, tb.y, tb.z, tb.w};
    // 4 dot2 chains (1 per gate): 32 dot2 = 64 MACs, fp32 accumulate
    float a0 = 0.0f, a1 = 0.0f, a2 = 0.0f, a3 = 0.0f;
#pragma unroll
    for (int k = 0; k < 8; ++k) {
      DOT2(a0, w16[0 * 8 + k], hv[k]);
      DOT2(a1, w16[1 * 8 + k], hv[k]);
      DOT2(a2, w16[2 * 8 + k], hv[k]);
      DOT2(a3, w16[3 * 8 + k], hv[k]);
    }
    // reduce-scatter, all-DPP: keep gate-bit_j == lane-bit_j ^ b2.
    // Round 1 (^1) and 2 (^2) are quad_perm; round 3 (^7, same gate on
    // both sides under the flipped mapping) is row_half_mirror.
    const int sel0 = (lane & 1) ^ b2;
    const int sel1 = ((lane >> 1) & 1) ^ b2;
    float u0 = sel0 ? a1 : a0, d0 = sel0 ? a0 : a1;
    float u1 = sel0 ? a3 : a2, d1 = sel0 ? a2 : a3;
    u0 += dppmov<0xB1>(d0);
    u1 += dppmov<0xB1>(d1);
    float uu = sel1 ? u1 : u0, dd = sel1 ? u0 : u1;
    uu += dppmov<0x4E>(dd);
    uu += dppmov<0x141>(uu);  // lane^7: other quad, same gate
    float z = uu + xz;
    // prefetch next step's xz (own gate only; vmcnt at next use)
    xz = XZ[(size_t)(e + 1) * 512 + p * 128 + elem];
    // unified per-lane gate nonlinearity
    float ex = __builtin_amdgcn_exp2f(z * kmul);
    float gq = __builtin_fmaf(smul, rcp_(1.0f + ex), badd);
    // assemble c,h (valid in p==0 lanes; others compute garbage, never read)
    float gf = dppmov<0xB1>(gq);  // sigmoid(zf) from lane^1
    float gt = dppmov<0x4E>(gq);  // tanh(zg)    from lane^2
    float go = dppmov<0x1B>(gq);  // sigmoid(zo) from lane^3
    c = __builtin_fmaf(gf, c, gq * gt);
    float ec = __builtin_amdgcn_exp2f(c * KT2);
    float th = __builtin_fmaf(2.0f, rcp_(1.0f + ec), -1.0f);
    float h = go * th;
    if (islead) {
      u16* hwp = (u16*)(&hbuf[cur ^ 1][0]);
      hwp[(elem >> 4) * 24 + (elem & 15)] = (u16)pkrtz(h, h);
      if (e > 0) hout[(size_t)(e - 1) * 128 + elem] = hrelu_prev;
      hrelu_prev = fmaxf(h, 0.0f);
    }
    BAR();
    cur ^= 1;
  }
  if (islead) hout[(size_t)(STEPS - 1) * 128 + elem] = hrelu_prev;
}

// ---------------------------------------------------------------------------
// K3: fused segment_min over edges + aggr projection (aggr never leaves the
// block). Block n: phase 1 (threads 0..127) computes aggr[n][j] = min over
// edges with eidx==n; phase 2 (all 256) does XZu[n] += Wih_u[:,64:192]@aggr.
// ---------------------------------------------------------------------------
__global__ __launch_bounds__(256) void k_aggminproj(
    const float* __restrict__ cva, const float* __restrict__ msg,
    const int* __restrict__ eidx, float* __restrict__ XZu) {
  const int n = blockIdx.x, tid = threadIdx.x;
  __shared__ float av[HM];
  if (tid < HM) {
    float m = __uint_as_float(0x7f800000u);  // +inf (segment_min identity)
    for (int e = 0; e < NEDGE; ++e) {
      if (eidx[e] == n) m = fminf(m, msg[(size_t)e * HM + tid]);
    }
    av[tid] = m;
  }
  __syncthreads();
  for (int j = tid; j < ZU; j += 256) {
    const float* wr = cva + O_WU + j * DU + FN;
    float acc = 0.0f;
#pragma unroll
    for (int k = 0; k < HM; ++k) acc += wr[k] * av[k];
    XZu[(size_t)n * ZU + j] += acc;
  }
}

// ---------------------------------------------------------------------------
// K5: fused (aggB computed in-block, never global).
// blocks [0,64): aggB[b] = segmin(upd) -> XZg[b] += Wih_g[:,0:128] @ aggB[b]
// blocks [64,128): chosen[b] -> XZa[b] = Wih_a[:,0:128] @ chosen[b] + biases
// ---------------------------------------------------------------------------
__global__ __launch_bounds__(256) void k_gproj(
    const float* __restrict__ cva, const float* __restrict__ upd,
    const int* __restrict__ bidx, const int* __restrict__ who,
    float* __restrict__ XZg, float* __restrict__ XZa) {
  const int blk = blockIdx.x, tid = threadIdx.x;
  __shared__ float buf[HU];
  __shared__ int satbw;
  if (blk < BG) {
    const int b = blk;
    if (tid < HU) {
      float m = __uint_as_float(0x7f800000u);
      for (int n = 0; n < NNODE; ++n) {
        if (bidx[n] == b) m = fminf(m, upd[(size_t)n * HU + tid]);
      }
      buf[tid] = m;
    }
    __syncthreads();
    if (tid < ZG) {
      const float* wr = cva + O_WG + tid * DG;
      float acc = 0.0f;
#pragma unroll
      for (int k = 0; k < HU; ++k) acc += wr[k] * buf[k];
      XZg[(size_t)b * ZG + tid] += acc;
    }
  } else {
    const int b = blk - BG;
    const int whoB = who[b];
    if (tid == 0) {
      int off = 0;
      for (int i = 0; i < NNODE; ++i) off += (bidx[i] < b) ? 1 : 0;
      const int adj = (whoB == 3) ? 2 : whoB;
      satbw = (b == 0) ? who[0] : (adj + off);
    }
    if (whoB == 3) {
      if (tid < HU) {
        float m = __uint_as_float(0x7f800000u);
        for (int n = 0; n < NNODE; ++n) {
          if (bidx[n] == b) m = fminf(m, upd[(size_t)n * HU + tid]);
        }
        buf[tid] = m;
      }
      __syncthreads();
    } else {
      __syncthreads();
      if (tid < HU) buf[tid] = upd[(size_t)satbw * HU + tid];
      __syncthreads();
    }
    if (tid < ZA) {
      const float* wr = cva + O_WA + tid * DA;
      float acc = cva[O_BA + tid];
#pragma unroll
      for (int k = 0; k < HU; ++k) acc += wr[k] * buf[k];
      XZa[(size_t)b * ZA + tid] = acc;
    }
  }
}

// ---------------------------------------------------------------------------
// K6: group LSTM chain (64 steps, H=64) + action chain + softmax + fp32 out.
// ---------------------------------------------------------------------------
__global__ __launch_bounds__(256, 2) void k_final(
    const float* __restrict__ cva, const float* __restrict__ XZg,
    const float* __restrict__ XZa, float* __restrict__ out) {
  const int j = threadIdx.x;
  __shared__ __align__(16) float hg[HG];
  __shared__ float zsg[ZG];
  __shared__ float grp[BG * HG];
  __shared__ float za[ZA];
  __shared__ float haL[HA];
  __shared__ float res[BG * HA];

  float wg[HG];
  {
    const float* wr = cva + O_WHG + j * HG;
#pragma unroll
    for (int k = 0; k < HG; ++k) wg[k] = wr[k];
  }
  if (j < HG) hg[j] = 0.0f;
  float cg = 0.0f;
  __syncthreads();
  for (int b = 0; b < BG; ++b) {
    float acc = XZg[(size_t)b * ZG + j];
#pragma unroll
    for (int k = 0; k < HG; ++k) acc += wg[k] * hg[k];
    zsg[j] = acc;
    __syncthreads();
    if (j < HG) {
      float zi = zsg[j], zf = zsg[HG + j], zg = zsg[2 * HG + j], zo = zsg[3 * HG + j];
      cg = sigf(zf) * cg + sigf(zi) * tanh_(zg);
      float h = sigf(zo) * tanh_(cg);
      hg[j] = h;
      grp[b * HG + j] = fmaxf(h, 0.0f);
    }
    __syncthreads();
  }

  float wa2[HG];
  float wha[HA];
  if (j < ZA) {
    const float* wr2 = cva + O_WA + j * DA + HU;
#pragma unroll
    for (int k = 0; k < HG; ++k) wa2[k] = wr2[k];
#pragma unroll
    for (int k = 0; k < HA; ++k) wha[k] = cva[O_WHA + j * HA + k];
  }
  if (j < HA) haL[j] = 0.0f;
  float ca = 0.0f;
  __syncthreads();
  for (int b = 0; b < BG; ++b) {
    if (j < ZA) {
      float acc = XZa[(size_t)b * ZA + j];
#pragma unroll
      for (int k = 0; k < HG; ++k) acc += wa2[k] * grp[b * HG + k];
#pragma unroll
      for (int k = 0; k < HA; ++k) acc += wha[k] * haL[k];
      za[j] = acc;
    }
    __syncthreads();
    if (j < HA) {
      float zi = za[j], zf = za[HA + j], zg = za[2 * HA + j], zo = za[3 * HA + j];
      ca = sigf(zf) * ca + sigf(zi) * tanh_(zg);
      float h = sigf(zo) * tanh_(ca);
      haL[j] = h;
      res[b * HA + j] = h;
    }
    __syncthreads();
  }
  if (j < BG) {
    float x0 = res[j * 4 + 0], x1 = res[j * 4 + 1];
    float x2 = res[j * 4 + 2], x3 = res[j * 4 + 3];
    float m = fmaxf(fmaxf(x0, x1), fmaxf(x2, x3));
    float e0 = __expf(x0 - m), e1 = __expf(x1 - m);
    float e2 = __expf(x2 - m), e3 = __expf(x3 - m);
    float s = e0 + e1 + e2 + e3;
    out[j * 4 + 0] = e0 / s;
    out[j * 4 + 1] = e1 / s;
    out[j * 4 + 2] = e2 / s;
    out[j * 4 + 3] = e3 / s;
  }
}

__global__ void k_zero(float* out) { out[threadIdx.x] = 0.0f; }

extern "C" void kernel_launch(void* const* d_in, const int* in_sizes, int n_in,
                              void* d_out, int out_size, void* d_ws, size_t ws_size,
                              hipStream_t stream) {
  const void* nodes = d_in[0];
  const void* gattr = d_in[1];
  const int* eidx  = (const int*)d_in[2];
  const int* nn    = (const int*)d_in[3];
  const int* ne    = (const int*)d_in[4];
  const int* bidx  = (const int*)d_in[5];
  const int* who   = (const int*)d_in[6];

  if (ws_size < (size_t)WS_FLOATS * 4) {
    k_zero<<<1, 256, 0, stream>>>((float*)d_out);
    return;
  }

  float* ws = (float*)d_ws;
  int* flagp = (int*)d_ws;
  float* cva = ws + CV;
  float* XZm = cva + O_XZM;
  float* XZu = cva + O_XZU;
  float* XZg = cva + O_XZG;
  float* XZa = cva + O_XZA;
  float* upd = cva + O_UPD;
  float* msg = XZm;  // overlay (delayed-store ordering; see k_chain comment)

  k_detect<<<1, 64, 0, stream>>>((const u32*)nodes, flagp);
  k_convert<<<(CONV_TOTAL + 255) / 256, 256, 0, stream>>>(
      nodes, gattr,
      d_in[7], d_in[8], d_in[9], d_in[10],
      d_in[11], d_in[12], d_in[13], d_in[14],
      d_in[15], d_in[16], d_in[17], d_in[18],
      d_in[19], d_in[20], d_in[21], d_in[22],
      flagp, cva);
  k_pre<<<NEDGE + NNODE + BG, 256, 0, stream>>>(cva, eidx, nn, ne, XZm, XZu, XZg);
  k_chain<NEDGE><<<1, 1024, 0, stream>>>(cva + O_WHM, XZm, msg);
  k_aggminproj<<<NNODE, 256, 0, stream>>>(cva, msg, eidx, XZu);
  k_chain<NNODE><<<1, 1024, 0, stream>>>(cva + O_WHU, XZu, upd);
  k_gproj<<<2 * BG, 256, 0, stream>>>(cva, upd, bidx, who, XZg, XZa);
  k_final<<<1, 256, 0, stream>>>(cva, XZg, XZa, (float*)d_out);
}

// Round 8
// 1293.189 us; speedup vs baseline: 1.1107x; 1.0045x over previous
//
#include <hip/hip_runtime.h>

typedef unsigned int u32;
typedef unsigned short u16;
typedef __fp16 h2 __attribute__((ext_vector_type(2)));

#define BG 64
#define NNODE 320
#define NEDGE 1280
#define TT 256
#define FN 64
#define FG 16
#define HM 128
#define HU 128
#define HG 64
#define HA 4
#define ZM 512
#define ZU 512
#define ZG 256
#define ZA 16
#define DM 144
#define DU 208
#define DG 144
#define DA 192

// ---- conversion-area layout (floats, relative to ws+64) ----
#define CV 64
#define O_NODES 0
#define O_GA    20480
#define O_WM    21504
#define O_WHM   95232
#define O_BM    160768
#define O_WU    161280
#define O_WHU   267776
#define O_BU    333312
#define O_WG    333824
#define O_WHG   370688
#define O_BG2   387072
#define O_WA    387328
#define O_WHA   390400
#define O_BA    390464
#define CONV_TOTAL 390480
#define O_XZM   390528
#define O_XZU   (O_XZM + NEDGE * ZM)
#define O_XZG   (O_XZU + NNODE * ZU)
#define O_XZA   (O_XZG + BG * ZG)
#define O_AGGR  (O_XZA + BG * ZA)
#define O_AGGB  (O_AGGR + NNODE * HM)
#define O_UPD   (O_AGGB + BG * HU)
#define WS_FLOATS (CV + O_UPD + NNODE * HU)

__device__ __forceinline__ float bf2f(u16 v) {
  return __uint_as_float(((u32)v) << 16);
}
__device__ __forceinline__ float rcp_(float x) { return __builtin_amdgcn_rcpf(x); }
__device__ __forceinline__ float sigf(float x) { return rcp_(1.0f + __expf(-x)); }
__device__ __forceinline__ float tanh_(float x) {
  float e = __expf(-2.0f * fabsf(x));
  float t = (1.0f - e) * rcp_(1.0f + e);
  return copysignf(t, x);
}
__device__ __forceinline__ float cvt(const void* p, int i, int flag) {
  return flag ? bf2f(((const u16*)p)[i]) : ((const float*)p)[i];
}

// pack 2 fp32 -> 2 fp16 (v_cvt_pkrtz_f16_f32, RTZ)
__device__ __forceinline__ h2 pk2(float a, float b) {
  return __builtin_amdgcn_cvt_pkrtz(a, b);
}
__device__ __forceinline__ u32 pk2u(float a, float b) {
  h2 r = __builtin_amdgcn_cvt_pkrtz(a, b);
  u32 out;
  __builtin_memcpy(&out, &r, 4);
  return out;
}

// fp16 dot2 with fp32 accumulate: D = a.h0*b.h0 + a.h1*b.h1 + D.
// Round-8: use the BUILTIN, not "v"-constrained asm. gfx950 has a unified
// VGPR/AGPR file and VOP3P can encode ACC sources; the asm's "v" constraint
// was FORCING a VGPR materialization (one accvgpr_read per use) of the
// AGPR-resident weight tile in rounds 2-7. The builtin lets the compiler
// either encode AGPR sources directly or keep the tile in arch VGPRs.
__device__ __forceinline__ float fdot2_(h2 a, h2 b, float c) {
#if __has_builtin(__builtin_amdgcn_fdot2)
  return __builtin_amdgcn_fdot2(a, b, c, false);
#else
  u32 ua, ub;
  __builtin_memcpy(&ua, &a, 4);
  __builtin_memcpy(&ub, &b, 4);
  asm("v_dot2_f32_f16 %0, %1, %2, %0" : "+v"(c) : "v"(ua), "v"(ub));
  return c;
#endif
}

// DPP cross-lane move (pure VALU, no DS pipe). Encodings:
// 0xB1 = quad_perm[1,0,3,2] (lane^1), 0x4E = quad_perm[2,3,0,1] (lane^2),
// 0x1B = quad_perm[3,2,1,0] (lane^3), 0x141 = row_half_mirror (lane^7
// within each 8-lane half-row).
template <int CTRL>
__device__ __forceinline__ float dppmov(float s) {
  return __int_as_float(
      __builtin_amdgcn_update_dpp(0, __float_as_int(s), CTRL, 0xF, 0xF, true));
}

// lgkmcnt-only barrier: LDS ordering without the vmcnt(0) drain that
// __syncthreads() emits. Global ops here are fire-and-forget stores (consumed
// by later kernels; visible at dispatch end) and prefetch loads (compiler
// inserts vmcnt wait at first use). See k_chain ordering proof in comments.
#define BAR() asm volatile("s_waitcnt lgkmcnt(0)\n\ts_barrier" ::: "memory")

// ---------------------------------------------------------------------------
// K-1: runtime dtype detector (unchanged; fp32 was detected).
// ---------------------------------------------------------------------------
__global__ void k_detect(const u32* __restrict__ raw, int* __restrict__ flagp) {
  const int t = threadIdx.x;  // 64 threads (1 wave)
  int zlo = 0, hits = 0;
  for (int k = t; k < 256; k += 64) {
    u32 w = raw[k];
    if ((w & 0xFFFFu) == 0u) zlo++;
    u32 m = (w >> 8) & 0x7Fu;
    if (m >= 40u && m <= 70u) hits++;
  }
#pragma unroll
  for (int off = 32; off; off >>= 1) {
    zlo += __shfl_down(zlo, off, 64);
    hits += __shfl_down(hits, off, 64);
  }
  if (t == 0) *flagp = (zlo < 128 && hits >= 128) ? 1 : 0;
}

// ---------------------------------------------------------------------------
// K0: convert weights/biases (+ t=255 slices) to fp32 in workspace.
// ---------------------------------------------------------------------------
__global__ __launch_bounds__(256) void k_convert(
    const void* nodes, const void* gattr,
    const void* Wm, const void* Whm, const void* bm1, const void* bm2,
    const void* Wu, const void* Whu, const void* bu1, const void* bu2,
    const void* Wg, const void* Whg, const void* bg1, const void* bg2,
    const void* Wa, const void* Wha, const void* ba1, const void* ba2,
    const int* __restrict__ flagp, float* __restrict__ dst) {
  const int flag = *flagp;
  const int i = blockIdx.x * 256 + threadIdx.x;
  if (i >= CONV_TOTAL) return;
  float v;
  if (i < O_GA) {
    int n = i >> 6, f = i & 63;
    v = cvt(nodes, (n * TT + (TT - 1)) * FN + f, flag);
  } else if (i < O_WM) {
    int l = i - O_GA; int b = l >> 4, g = l & 15;
    v = cvt(gattr, (b * TT + (TT - 1)) * FG + g, flag);
  } else if (i < O_BM) {
    v = (i < O_WHM) ? cvt(Wm, i - O_WM, flag) : cvt(Whm, i - O_WHM, flag);
  } else if (i < O_WU) {
    int l = i - O_BM; v = cvt(bm1, l, flag) + cvt(bm2, l, flag);
  } else if (i < O_BU) {
    v = (i < O_WHU) ? cvt(Wu, i - O_WU, flag) : cvt(Whu, i - O_WHU, flag);
  } else if (i < O_WG) {
    int l = i - O_BU; v = cvt(bu1, l, flag) + cvt(bu2, l, flag);
  } else if (i < O_BG2) {
    v = (i < O_WHG) ? cvt(Wg, i - O_WG, flag) : cvt(Whg, i - O_WHG, flag);
  } else if (i < O_WA) {
    int l = i - O_BG2; v = cvt(bg1, l, flag) + cvt(bg2, l, flag);
  } else if (i < O_WHA) {
    v = cvt(Wa, i - O_WA, flag);
  } else if (i < O_BA) {
    v = cvt(Wha, i - O_WHA, flag);
  } else {
    int l = i - O_BA; v = cvt(ba1, l, flag) + cvt(ba2, l, flag);
  }
  dst[i] = v;
}

// ---------------------------------------------------------------------------
// K1: parallel precompute of input projections at t = T-1 (unchanged).
// ---------------------------------------------------------------------------
__global__ __launch_bounds__(256) void k_pre(
    const float* __restrict__ cva,
    const int* __restrict__ eidx, const int* __restrict__ num_nodes,
    const int* __restrict__ num_edges,
    float* __restrict__ XZm, float* __restrict__ XZu, float* __restrict__ XZg) {
  const int blk = blockIdx.x, tid = threadIdx.x;
  __shared__ float xv[FN];
  __shared__ float gav[FG];
  __shared__ int sgr;
  const float* nodes255 = cva + O_NODES;
  const float* ga255 = cva + O_GA;

  if (blk < NEDGE) {
    const int e = blk;
    if (tid == 0) {
      int g = 0, acc = 0;
      while (g < BG) { int c = num_edges[g]; if (e < acc + c) break; acc += c; ++g; }
      if (g >= BG) g = BG - 1;
      sgr = g;
    }
    const int srcn = eidx[e];  // faithful: src == tgt == edge_indices[0]
    if (tid < FN) xv[tid] = nodes255[srcn * FN + tid];
    __syncthreads();
    if (tid < FG) gav[tid] = ga255[sgr * FG + tid];
    __syncthreads();
    for (int j = tid; j < ZM; j += 256) {
      const float* wr = cva + O_WM + j * DM;
      float acc = cva[O_BM + j];
#pragma unroll
      for (int d = 0; d < FN; ++d) acc += (wr[d] + wr[FN + d]) * xv[d];
#pragma unroll
      for (int d = 0; d < FG; ++d) acc += wr[2 * FN + d] * gav[d];
      XZm[(size_t)e * ZM + j] = acc;
    }
  } else if (blk < NEDGE + NNODE) {
    const int n = blk - NEDGE;
    if (tid == 0) {
      int g = 0, acc = 0;
      while (g < BG) { int c = num_nodes[g]; if (n < acc + c) break; acc += c; ++g; }
      if (g >= BG) g = BG - 1;
      sgr = g;
    }
    if (tid < FN) xv[tid] = nodes255[n * FN + tid];
    __syncthreads();
    if (tid < FG) gav[tid] = ga255[sgr * FG + tid];
    __syncthreads();
    for (int j = tid; j < ZU; j += 256) {
      const float* wr = cva + O_WU + j * DU;
      float acc = cva[O_BU + j];
#pragma unroll
      for (int d = 0; d < FN; ++d) acc += wr[d] * xv[d];
#pragma unroll
      for (int d = 0; d < FG; ++d) acc += wr[FN + HM + d] * gav[d];
      XZu[(size_t)n * ZU + j] = acc;
    }
  } else {
    const int b = blk - NEDGE - NNODE;
    if (tid < FG) gav[tid] = ga255[b * FG + tid];
    __syncthreads();
    if (tid < ZG) {
      const float* wr = cva + O_WG + tid * DG;
      float acc = cva[O_BG2 + tid];
#pragma unroll
      for (int d = 0; d < FG; ++d) acc += wr[HU + d] * gav[d];
      XZg[(size_t)b * ZG + tid] = acc;
    }
  }
}

// ---------------------------------------------------------------------------
// K2/K4: LSTM chain. 1024 threads (16 waves). fp16-dot2 MAC core via builtin.
//
// 8-lane k-group = 8 contiguous lanes (round-5 layout, all-DPP exchange):
//   kc = lane&7 (k-chunk of 16 h), grp = lane>>3, elem = wv*8+grp.
//   Gate mapping XOR-flipped in odd quads: p = (lane&3) ^ 3*((lane>>2)&1);
//   lane i and i^7 own the same gate -> reduce round 3 = row_half_mirror.
// MAC: weights as 32 packed-fp16 pairs (h2), h read from LDS as packed-fp16
// pairs; 32 v_dot2_f32_f16 per lane = 64 MACs, fp32 accumulate. xz (input
// projection) stays exact fp32; only the recurrent term carries fp16
// rounding (~1e-3 abs on z; verified absmax 0.002 in round 7).
//
// h buffer: fp16, double-buffered, 8 chunks x 12 u32 (8 data + 4 pad).
// Chunk kc at u32 offset kc*12: 16B-aligned (b128-legal), banks
// {0,12,24,4,16,28,8,20} distinct; second b128 at +4 likewise. Lead lanes
// write their single h as u16 at halfword index (elem>>4)*24 + (elem&15).
//
// Ordering proof for overlay (k_msg: hout overlays XZ region):
//   store of step e-1's h at step e touches XZ floats [(e-1)*128,(e)*128)
//   i.e. XZ row (e-1)/4 <= e-1; every wave consumed that row's loads
//   (vmcnt-waited at its z compute) before passing barrier e-1; prefetch at
//   step e reads row e+1 > (e-1)/4. No in-flight load can see the store.
//   Unconditional prefetch of row STEPS reads one row past XZ: still inside
//   the workspace (XZu follows XZm, XZg follows XZu); value unused.
// ---------------------------------------------------------------------------
template <int STEPS>
__global__ __launch_bounds__(1024, 4) void k_chain(
    const float* __restrict__ Whh, const float* __restrict__ XZ,
    float* __restrict__ hout) {
  const int lane = threadIdx.x & 63;
  const int wv = threadIdx.x >> 6;            // wave 0..15
  const int kc = lane & 7;                    // k-chunk 0..7 (16 h each)
  const int grp = lane >> 3;                  // group-in-wave 0..7
  const int elem = wv * 8 + grp;              // element 0..127
  const int b2 = (lane >> 2) & 1;             // odd-quad flag
  const int p = (lane & 3) ^ (3 * b2);        // gate this lane finalizes
  const bool islead = ((lane & 7) == 0);      // lane 8g+0: p==0, one per group
  __shared__ u32 hbuf[2][96];                 // fp16 h: 8 chunks x (8+4) u32

  h2 w16[32];  // Whh rows {pp*128+elem}, cols kc*16..+15, packed fp16 pairs
#pragma unroll
  for (int pp = 0; pp < 4; ++pp) {
    const float4* wr =
        (const float4*)(Whh + (size_t)(pp * 128 + elem) * 128 + kc * 16);
#pragma unroll
    for (int q = 0; q < 4; ++q) {
      float4 t = wr[q];
      w16[pp * 8 + 2 * q] = pk2(t.x, t.y);
      w16[pp * 8 + 2 * q + 1] = pk2(t.z, t.w);
    }
  }
  // per-lane nonlinearity constants: sigmoid(z)=rcp(1+exp2(-z*log2e));
  // tanh(z)=2*rcp(1+exp2(-2z*log2e))-1. Unified: fma(smul, rcp(1+exp2(z*kmul)), badd)
  const float LOG2E = 1.4426950408889634f;
  const float kmul = (p == 2) ? (-2.0f * LOG2E) : (-LOG2E);
  const float smul = (p == 2) ? 2.0f : 1.0f;
  const float badd = (p == 2) ? -1.0f : 0.0f;
  const float KT2 = -2.0f * LOG2E;  // for tanh(c)

  if (threadIdx.x < 192) ((u32*)hbuf)[threadIdx.x] = 0u;  // h=0 (fp16 zero)
  float c = 0.0f;
  float hrelu_prev = 0.0f;
  float xz = XZ[p * 128 + elem];
  BAR();
  int cur = 0;
  for (int e = 0; e < STEPS; ++e) {
    // h chunk (16 fp16 = 8 u32) from LDS, two b128, conflict-free broadcast
    const uint4* hb = (const uint4*)&hbuf[cur][kc * 12];
    uint4 ta = hb[0], tb = hb[1];
    u32 hraw[8] = {ta.x, ta.y, ta.z, ta.w, tb.x, tb.y, tb.z, tb.w};
    h2 hv[8];
#pragma unroll
    for (int k = 0; k < 8; ++k) __builtin_memcpy(&hv[k], &hraw[k], 4);
    // 4 dot2 chains (1 per gate): 32 dot2 = 64 MACs, fp32 accumulate
    float a0 = 0.0f, a1 = 0.0f, a2 = 0.0f, a3 = 0.0f;
#pragma unroll
    for (int k = 0; k < 8; ++k) {
      a0 = fdot2_(w16[0 * 8 + k], hv[k], a0);
      a1 = fdot2_(w16[1 * 8 + k], hv[k], a1);
      a2 = fdot2_(w16[2 * 8 + k], hv[k], a2);
      a3 = fdot2_(w16[3 * 8 + k], hv[k], a3);
    }
    // reduce-scatter, all-DPP: keep gate-bit_j == lane-bit_j ^ b2.
    // Round 1 (^1) and 2 (^2) are quad_perm; round 3 (^7, same gate on
    // both sides under the flipped mapping) is row_half_mirror.
    const int sel0 = (lane & 1) ^ b2;
    const int sel1 = ((lane >> 1) & 1) ^ b2;
    float u0 = sel0 ? a1 : a0, d0 = sel0 ? a0 : a1;
    float u1 = sel0 ? a3 : a2, d1 = sel0 ? a2 : a3;
    u0 += dppmov<0xB1>(d0);
    u1 += dppmov<0xB1>(d1);
    float uu = sel1 ? u1 : u0, dd = sel1 ? u0 : u1;
    uu += dppmov<0x4E>(dd);
    uu += dppmov<0x141>(uu);  // lane^7: other quad, same gate
    float z = uu + xz;
    // prefetch next step's xz (own gate only; vmcnt at next use)
    xz = XZ[(size_t)(e + 1) * 512 + p * 128 + elem];
    // unified per-lane gate nonlinearity
    float ex = __builtin_amdgcn_exp2f(z * kmul);
    float gq = __builtin_fmaf(smul, rcp_(1.0f + ex), badd);
    // assemble c,h (valid in p==0 lanes; others compute garbage, never read)
    float gf = dppmov<0xB1>(gq);  // sigmoid(zf) from lane^1
    float gt = dppmov<0x4E>(gq);  // tanh(zg)    from lane^2
    float go = dppmov<0x1B>(gq);  // sigmoid(zo) from lane^3
    c = __builtin_fmaf(gf, c, gq * gt);
    float ec = __builtin_amdgcn_exp2f(c * KT2);
    float th = __builtin_fmaf(2.0f, rcp_(1.0f + ec), -1.0f);
    float h = go * th;
    if (islead) {
      u16* hwp = (u16*)(&hbuf[cur ^ 1][0]);
      hwp[(elem >> 4) * 24 + (elem & 15)] = (u16)pk2u(h, h);
      if (e > 0) hout[(size_t)(e - 1) * 128 + elem] = hrelu_prev;
      hrelu_prev = fmaxf(h, 0.0f);
    }
    BAR();
    cur ^= 1;
  }
  if (islead) hout[(size_t)(STEPS - 1) * 128 + elem] = hrelu_prev;
}

// ---------------------------------------------------------------------------
// K3: fused segment_min over edges + aggr projection (aggr never leaves the
// block). Block n: phase 1 (threads 0..127) computes aggr[n][j] = min over
// edges with eidx==n; phase 2 (all 256) does XZu[n] += Wih_u[:,64:192]@aggr.
// ---------------------------------------------------------------------------
__global__ __launch_bounds__(256) void k_aggminproj(
    const float* __restrict__ cva, const float* __restrict__ msg,
    const int* __restrict__ eidx, float* __restrict__ XZu) {
  const int n = blockIdx.x, tid = threadIdx.x;
  __shared__ float av[HM];
  if (tid < HM) {
    float m = __uint_as_float(0x7f800000u);  // +inf (segment_min identity)
    for (int e = 0; e < NEDGE; ++e) {
      if (eidx[e] == n) m = fminf(m, msg[(size_t)e * HM + tid]);
    }
    av[tid] = m;
  }
  __syncthreads();
  for (int j = tid; j < ZU; j += 256) {
    const float* wr = cva + O_WU + j * DU + FN;
    float acc = 0.0f;
#pragma unroll
    for (int k = 0; k < HM; ++k) acc += wr[k] * av[k];
    XZu[(size_t)n * ZU + j] += acc;
  }
}

// ---------------------------------------------------------------------------
// K5: fused (aggB computed in-block, never global).
// blocks [0,64): aggB[b] = segmin(upd) -> XZg[b] += Wih_g[:,0:128] @ aggB[b]
// blocks [64,128): chosen[b] -> XZa[b] = Wih_a[:,0:128] @ chosen[b] + biases
// ---------------------------------------------------------------------------
__global__ __launch_bounds__(256) void k_gproj(
    const float* __restrict__ cva, const float* __restrict__ upd,
    const int* __restrict__ bidx, const int* __restrict__ who,
    float* __restrict__ XZg, float* __restrict__ XZa) {
  const int blk = blockIdx.x, tid = threadIdx.x;
  __shared__ float buf[HU];
  __shared__ int satbw;
  if (blk < BG) {
    const int b = blk;
    if (tid < HU) {
      float m = __uint_as_float(0x7f800000u);
      for (int n = 0; n < NNODE; ++n) {
        if (bidx[n] == b) m = fminf(m, upd[(size_t)n * HU + tid]);
      }
      buf[tid] = m;
    }
    __syncthreads();
    if (tid < ZG) {
      const float* wr = cva + O_WG + tid * DG;
      float acc = 0.0f;
#pragma unroll
      for (int k = 0; k < HU; ++k) acc += wr[k] * buf[k];
      XZg[(size_t)b * ZG + tid] += acc;
    }
  } else {
    const int b = blk - BG;
    const int whoB = who[b];
    if (tid == 0) {
      int off = 0;
      for (int i = 0; i < NNODE; ++i) off += (bidx[i] < b) ? 1 : 0;
      const int adj = (whoB == 3) ? 2 : whoB;
      satbw = (b == 0) ? who[0] : (adj + off);
    }
    if (whoB == 3) {
      if (tid < HU) {
        float m = __uint_as_float(0x7f800000u);
        for (int n = 0; n < NNODE; ++n) {
          if (bidx[n] == b) m = fminf(m, upd[(size_t)n * HU + tid]);
        }
        buf[tid] = m;
      }
      __syncthreads();
    } else {
      __syncthreads();
      if (tid < HU) buf[tid] = upd[(size_t)satbw * HU + tid];
      __syncthreads();
    }
    if (tid < ZA) {
      const float* wr = cva + O_WA + tid * DA;
      float acc = cva[O_BA + tid];
#pragma unroll
      for (int k = 0; k < HU; ++k) acc += wr[k] * buf[k];
      XZa[(size_t)b * ZA + tid] = acc;
    }
  }
}

// ---------------------------------------------------------------------------
// K6: group LSTM chain (64 steps, H=64) + action chain + softmax + fp32 out.
// ---------------------------------------------------------------------------
__global__ __launch_bounds__(256, 2) void k_final(
    const float* __restrict__ cva, const float* __restrict__ XZg,
    const float* __restrict__ XZa, float* __restrict__ out) {
  const int j = threadIdx.x;
  __shared__ __align__(16) float hg[HG];
  __shared__ float zsg[ZG];
  __shared__ float grp[BG * HG];
  __shared__ float za[ZA];
  __shared__ float haL[HA];
  __shared__ float res[BG * HA];

  float wg[HG];
  {
    const float* wr = cva + O_WHG + j * HG;
#pragma unroll
    for (int k = 0; k < HG; ++k) wg[k] = wr[k];
  }
  if (j < HG) hg[j] = 0.0f;
  float cg = 0.0f;
  __syncthreads();
  for (int b = 0; b < BG; ++b) {
    float acc = XZg[(size_t)b * ZG + j];
#pragma unroll
    for (int k = 0; k < HG; ++k) acc += wg[k] * hg[k];
    zsg[j] = acc;
    __syncthreads();
    if (j < HG) {
      float zi = zsg[j], zf = zsg[HG + j], zg = zsg[2 * HG + j], zo = zsg[3 * HG + j];
      cg = sigf(zf) * cg + sigf(zi) * tanh_(zg);
      float h = sigf(zo) * tanh_(cg);
      hg[j] = h;
      grp[b * HG + j] = fmaxf(h, 0.0f);
    }
    __syncthreads();
  }

  float wa2[HG];
  float wha[HA];
  if (j < ZA) {
    const float* wr2 = cva + O_WA + j * DA + HU;
#pragma unroll
    for (int k = 0; k < HG; ++k) wa2[k] = wr2[k];
#pragma unroll
    for (int k = 0; k < HA; ++k) wha[k] = cva[O_WHA + j * HA + k];
  }
  if (j < HA) haL[j] = 0.0f;
  float ca = 0.0f;
  __syncthreads();
  for (int b = 0; b < BG; ++b) {
    if (j < ZA) {
      float acc = XZa[(size_t)b * ZA + j];
#pragma unroll
      for (int k = 0; k < HG; ++k) acc += wa2[k] * grp[b * HG + k];
#pragma unroll
      for (int k = 0; k < HA; ++k) acc += wha[k] * haL[k];
      za[j] = acc;
    }
    __syncthreads();
    if (j < HA) {
      float zi = za[j], zf = za[HA + j], zg = za[2 * HA + j], zo = za[3 * HA + j];
      ca = sigf(zf) * ca + sigf(zi) * tanh_(zg);
      float h = sigf(zo) * tanh_(ca);
      haL[j] = h;
      res[b * HA + j] = h;
    }
    __syncthreads();
  }
  if (j < BG) {
    float x0 = res[j * 4 + 0], x1 = res[j * 4 + 1];
    float x2 = res[j * 4 + 2], x3 = res[j * 4 + 3];
    float m = fmaxf(fmaxf(x0, x1), fmaxf(x2, x3));
    float e0 = __expf(x0 - m), e1 = __expf(x1 - m);
    float e2 = __expf(x2 - m), e3 = __expf(x3 - m);
    float s = e0 + e1 + e2 + e3;
    out[j * 4 + 0] = e0 / s;
    out[j * 4 + 1] = e1 / s;
    out[j * 4 + 2] = e2 / s;
    out[j * 4 + 3] = e3 / s;
  }
}

__global__ void k_zero(float* out) { out[threadIdx.x] = 0.0f; }

extern "C" void kernel_launch(void* const* d_in, const int* in_sizes, int n_in,
                              void* d_out, int out_size, void* d_ws, size_t ws_size,
                              hipStream_t stream) {
  const void* nodes = d_in[0];
  const void* gattr = d_in[1];
  const int* eidx  = (const int*)d_in[2];
  const int* nn    = (const int*)d_in[3];
  const int* ne    = (const int*)d_in[4];
  const int* bidx  = (const int*)d_in[5];
  const int* who   = (const int*)d_in[6];

  if (ws_size < (size_t)WS_FLOATS * 4) {
    k_zero<<<1, 256, 0, stream>>>((float*)d_out);
    return;
  }

  float* ws = (float*)d_ws;
  int* flagp = (int*)d_ws;
  float* cva = ws + CV;
  float* XZm = cva + O_XZM;
  float* XZu = cva + O_XZU;
  float* XZg = cva + O_XZG;
  float* XZa = cva + O_XZA;
  float* upd = cva + O_UPD;
  float* msg = XZm;  // overlay (delayed-store ordering; see k_chain comment)

  k_detect<<<1, 64, 0, stream>>>((const u32*)nodes, flagp);
  k_convert<<<(CONV_TOTAL + 255) / 256, 256, 0, stream>>>(
      nodes, gattr,
      d_in[7], d_in[8], d_in[9], d_in[10],
      d_in[11], d_in[12], d_in[13], d_in[14],
      d_in[15], d_in[16], d_in[17], d_in[18],
      d_in[19], d_in[20], d_in[21], d_in[22],
      flagp, cva);
  k_pre<<<NEDGE + NNODE + BG, 256, 0, stream>>>(cva, eidx, nn, ne, XZm, XZu, XZg);
  k_chain<NEDGE><<<1, 1024, 0, stream>>>(cva + O_WHM, XZm, msg);
  k_aggminproj<<<NNODE, 256, 0, stream>>>(cva, msg, eidx, XZu);
  k_chain<NNODE><<<1, 1024, 0, stream>>>(cva + O_WHU, XZu, upd);
  k_gproj<<<2 * BG, 256, 0, stream>>>(cva, upd, bidx, who, XZg, XZa);
  k_final<<<1, 256, 0, stream>>>(cva, XZg, XZa, (float*)d_out);
}

// Round 9
// 1143.061 us; speedup vs baseline: 1.2566x; 1.1313x over previous
//
#include <hip/hip_runtime.h>

typedef unsigned int u32;
typedef unsigned short u16;
typedef __fp16 h2 __attribute__((ext_vector_type(2)));

#define BG 64
#define NNODE 320
#define NEDGE 1280
#define TT 256
#define FN 64
#define FG 16
#define HM 128
#define HU 128
#define HG 64
#define HA 4
#define ZM 512
#define ZU 512
#define ZG 256
#define ZA 16
#define DM 144
#define DU 208
#define DG 144
#define DA 192

// ---- conversion-area layout (floats, relative to ws+64) ----
#define CV 64
#define O_NODES 0
#define O_GA    20480
#define O_WM    21504
#define O_WHM   95232
#define O_BM    160768
#define O_WU    161280
#define O_WHU   267776
#define O_BU    333312
#define O_WG    333824
#define O_WHG   370688
#define O_BG2   387072
#define O_WA    387328
#define O_WHA   390400
#define O_BA    390464
#define CONV_TOTAL 390480
#define O_XZM   390528
#define O_XZU   (O_XZM + NEDGE * ZM)
#define O_XZG   (O_XZU + NNODE * ZU)
#define O_XZA   (O_XZG + BG * ZG)
#define O_AGGR  (O_XZA + BG * ZA)
#define O_AGGB  (O_AGGR + NNODE * HM)
#define O_UPD   (O_AGGB + BG * HU)
#define WS_FLOATS (CV + O_UPD + NNODE * HU)

__device__ __forceinline__ float bf2f(u16 v) {
  return __uint_as_float(((u32)v) << 16);
}
__device__ __forceinline__ float rcp_(float x) { return __builtin_amdgcn_rcpf(x); }
__device__ __forceinline__ float sigf(float x) { return rcp_(1.0f + __expf(-x)); }
__device__ __forceinline__ float tanh_(float x) {
  float e = __expf(-2.0f * fabsf(x));
  float t = (1.0f - e) * rcp_(1.0f + e);
  return copysignf(t, x);
}
__device__ __forceinline__ float cvt(const void* p, int i, int flag) {
  return flag ? bf2f(((const u16*)p)[i]) : ((const float*)p)[i];
}

// pack 2 fp32 -> 2 fp16 (v_cvt_pkrtz_f16_f32, RTZ)
__device__ __forceinline__ h2 pk2(float a, float b) {
  return __builtin_amdgcn_cvt_pkrtz(a, b);
}
__device__ __forceinline__ u32 pk2u(float a, float b) {
  h2 r = __builtin_amdgcn_cvt_pkrtz(a, b);
  u32 out;
  __builtin_memcpy(&out, &r, 4);
  return out;
}

// fp16 dot2 with fp32 accumulate: D = a.h0*b.h0 + a.h1*b.h1 + D.
__device__ __forceinline__ float fdot2_(h2 a, h2 b, float c) {
#if __has_builtin(__builtin_amdgcn_fdot2)
  return __builtin_amdgcn_fdot2(a, b, c, false);
#else
  u32 ua, ub;
  __builtin_memcpy(&ua, &a, 4);
  __builtin_memcpy(&ub, &b, 4);
  asm("v_dot2_f32_f16 %0, %1, %2, %0" : "+v"(c) : "v"(ua), "v"(ub));
  return c;
#endif
}

// DPP cross-lane move (pure VALU, no DS pipe). Encodings:
// 0xB1 = quad_perm[1,0,3,2] (lane^1), 0x4E = quad_perm[2,3,0,1] (lane^2),
// 0x1B = quad_perm[3,2,1,0] (lane^3).
template <int CTRL>
__device__ __forceinline__ float dppmov(float s) {
  return __int_as_float(
      __builtin_amdgcn_update_dpp(0, __float_as_int(s), CTRL, 0xF, 0xF, true));
}

// lgkmcnt-only barrier: LDS ordering without the vmcnt(0) drain that
// __syncthreads() emits. Global ops here are fire-and-forget stores (consumed
// by later kernels; visible at dispatch end) and prefetch loads (compiler
// inserts vmcnt wait at first use). See k_chain ordering proof in comments.
#define BAR() asm volatile("s_waitcnt lgkmcnt(0)\n\ts_barrier" ::: "memory")

// ---------------------------------------------------------------------------
// K-1: runtime dtype detector (unchanged; fp32 was detected).
// ---------------------------------------------------------------------------
__global__ void k_detect(const u32* __restrict__ raw, int* __restrict__ flagp) {
  const int t = threadIdx.x;  // 64 threads (1 wave)
  int zlo = 0, hits = 0;
  for (int k = t; k < 256; k += 64) {
    u32 w = raw[k];
    if ((w & 0xFFFFu) == 0u) zlo++;
    u32 m = (w >> 8) & 0x7Fu;
    if (m >= 40u && m <= 70u) hits++;
  }
#pragma unroll
  for (int off = 32; off; off >>= 1) {
    zlo += __shfl_down(zlo, off, 64);
    hits += __shfl_down(hits, off, 64);
  }
  if (t == 0) *flagp = (zlo < 128 && hits >= 128) ? 1 : 0;
}

// ---------------------------------------------------------------------------
// K0: convert weights/biases (+ t=255 slices) to fp32 in workspace.
// ---------------------------------------------------------------------------
__global__ __launch_bounds__(256) void k_convert(
    const void* nodes, const void* gattr,
    const void* Wm, const void* Whm, const void* bm1, const void* bm2,
    const void* Wu, const void* Whu, const void* bu1, const void* bu2,
    const void* Wg, const void* Whg, const void* bg1, const void* bg2,
    const void* Wa, const void* Wha, const void* ba1, const void* ba2,
    const int* __restrict__ flagp, float* __restrict__ dst) {
  const int flag = *flagp;
  const int i = blockIdx.x * 256 + threadIdx.x;
  if (i >= CONV_TOTAL) return;
  float v;
  if (i < O_GA) {
    int n = i >> 6, f = i & 63;
    v = cvt(nodes, (n * TT + (TT - 1)) * FN + f, flag);
  } else if (i < O_WM) {
    int l = i - O_GA; int b = l >> 4, g = l & 15;
    v = cvt(gattr, (b * TT + (TT - 1)) * FG + g, flag);
  } else if (i < O_BM) {
    v = (i < O_WHM) ? cvt(Wm, i - O_WM, flag) : cvt(Whm, i - O_WHM, flag);
  } else if (i < O_WU) {
    int l = i - O_BM; v = cvt(bm1, l, flag) + cvt(bm2, l, flag);
  } else if (i < O_BU) {
    v = (i < O_WHU) ? cvt(Wu, i - O_WU, flag) : cvt(Whu, i - O_WHU, flag);
  } else if (i < O_WG) {
    int l = i - O_BU; v = cvt(bu1, l, flag) + cvt(bu2, l, flag);
  } else if (i < O_BG2) {
    v = (i < O_WHG) ? cvt(Wg, i - O_WG, flag) : cvt(Whg, i - O_WHG, flag);
  } else if (i < O_WA) {
    int l = i - O_BG2; v = cvt(bg1, l, flag) + cvt(bg2, l, flag);
  } else if (i < O_WHA) {
    v = cvt(Wa, i - O_WA, flag);
  } else if (i < O_BA) {
    v = cvt(Wha, i - O_WHA, flag);
  } else {
    int l = i - O_BA; v = cvt(ba1, l, flag) + cvt(ba2, l, flag);
  }
  dst[i] = v;
}

// ---------------------------------------------------------------------------
// K1: parallel precompute of input projections at t = T-1 (unchanged).
// ---------------------------------------------------------------------------
__global__ __launch_bounds__(256) void k_pre(
    const float* __restrict__ cva,
    const int* __restrict__ eidx, const int* __restrict__ num_nodes,
    const int* __restrict__ num_edges,
    float* __restrict__ XZm, float* __restrict__ XZu, float* __restrict__ XZg) {
  const int blk = blockIdx.x, tid = threadIdx.x;
  __shared__ float xv[FN];
  __shared__ float gav[FG];
  __shared__ int sgr;
  const float* nodes255 = cva + O_NODES;
  const float* ga255 = cva + O_GA;

  if (blk < NEDGE) {
    const int e = blk;
    if (tid == 0) {
      int g = 0, acc = 0;
      while (g < BG) { int c = num_edges[g]; if (e < acc + c) break; acc += c; ++g; }
      if (g >= BG) g = BG - 1;
      sgr = g;
    }
    const int srcn = eidx[e];  // faithful: src == tgt == edge_indices[0]
    if (tid < FN) xv[tid] = nodes255[srcn * FN + tid];
    __syncthreads();
    if (tid < FG) gav[tid] = ga255[sgr * FG + tid];
    __syncthreads();
    for (int j = tid; j < ZM; j += 256) {
      const float* wr = cva + O_WM + j * DM;
      float acc = cva[O_BM + j];
#pragma unroll
      for (int d = 0; d < FN; ++d) acc += (wr[d] + wr[FN + d]) * xv[d];
#pragma unroll
      for (int d = 0; d < FG; ++d) acc += wr[2 * FN + d] * gav[d];
      XZm[(size_t)e * ZM + j] = acc;
    }
  } else if (blk < NEDGE + NNODE) {
    const int n = blk - NEDGE;
    if (tid == 0) {
      int g = 0, acc = 0;
      while (g < BG) { int c = num_nodes[g]; if (n < acc + c) break; acc += c; ++g; }
      if (g >= BG) g = BG - 1;
      sgr = g;
    }
    if (tid < FN) xv[tid] = nodes255[n * FN + tid];
    __syncthreads();
    if (tid < FG) gav[tid] = ga255[sgr * FG + tid];
    __syncthreads();
    for (int j = tid; j < ZU; j += 256) {
      const float* wr = cva + O_WU + j * DU;
      float acc = cva[O_BU + j];
#pragma unroll
      for (int d = 0; d < FN; ++d) acc += wr[d] * xv[d];
#pragma unroll
      for (int d = 0; d < FG; ++d) acc += wr[FN + HM + d] * gav[d];
      XZu[(size_t)n * ZU + j] = acc;
    }
  } else {
    const int b = blk - NEDGE - NNODE;
    if (tid < FG) gav[tid] = ga255[b * FG + tid];
    __syncthreads();
    if (tid < ZG) {
      const float* wr = cva + O_WG + tid * DG;
      float acc = cva[O_BG2 + tid];
#pragma unroll
      for (int d = 0; d < FG; ++d) acc += wr[HU + d] * gav[d];
      XZg[(size_t)b * ZG + tid] = acc;
    }
  }
}

// ---------------------------------------------------------------------------
// K2/K4: LSTM chain. Round-9: 512 threads (8 waves), FULL-ROW ownership.
//
// Thread t owns the complete Whh row (t&3)*128 + (t>>2): gate p = t&3 of
// element elem = t>>2, all K=128 as 64 packed-fp16 pairs (64 VGPRs; at
// __launch_bounds__(512,2) the budget is 256/wave, so the tile fits arch
// VGPRs with slack). Each lane reads the FULL h from LDS (16 broadcast
// ds_read_b128 — all lanes same address, conflict-free) and accumulates 64
// dot2 in 4 independent chains -> z complete IN-LANE: the 3-round
// reduce-scatter of rounds 2-8 is deleted entirely. The 4 gates of element
// e sit in quad lanes 4e..4e+3, so c/h assembly keeps the same 3 quad_perm
// gathers (no gate-flip needed). Overhead (nonlin, bookkeeping, barrier) is
// replicated over 8 waves instead of 16 -> total issue/step ~halves.
//
// h buffer: fp16, double-buffered, 64 data u32 (+16 pad). Lead lanes (p==0,
// 16/wave) write h[elem] as u16: per wave 16 consecutive halfwords = 32 B,
// 2 lanes/bank = free. Reads are wave-uniform broadcasts.
//
// Ordering proof for overlay (k_msg: hout overlays XZ region):
//   store of step e-1's h at step e touches XZ floats [(e-1)*128,(e)*128)
//   i.e. XZ row (e-1)/4 <= e-1; every wave consumed that row's loads
//   (vmcnt-waited at its z compute) before passing barrier e-1; prefetch at
//   step e reads row e+1 > (e-1)/4. No in-flight load can see the store.
//   Unconditional prefetch of row STEPS reads one row past XZ: still inside
//   the workspace (XZu follows XZm, XZg follows XZu); value unused.
// ---------------------------------------------------------------------------
template <int STEPS>
__global__ __launch_bounds__(512, 2) void k_chain(
    const float* __restrict__ Whh, const float* __restrict__ XZ,
    float* __restrict__ hout) {
  const int t = threadIdx.x;              // 0..511
  const int p = t & 3;                    // gate this lane owns
  const int elem = t >> 2;                // element 0..127
  const bool islead = (p == 0);
  __shared__ u32 hbuf[2][80];             // fp16 h: 64 data + 16 pad u32

  h2 w16[64];  // full row p*128+elem of Whh, packed fp16 pairs
  {
    const float4* wr = (const float4*)(Whh + (size_t)(p * 128 + elem) * 128);
#pragma unroll
    for (int q = 0; q < 32; ++q) {
      float4 v = wr[q];
      w16[2 * q] = pk2(v.x, v.y);
      w16[2 * q + 1] = pk2(v.z, v.w);
    }
  }
  // per-lane nonlinearity constants: sigmoid(z)=rcp(1+exp2(-z*log2e));
  // tanh(z)=2*rcp(1+exp2(-2z*log2e))-1. Unified: fma(smul, rcp(1+exp2(z*kmul)), badd)
  const float LOG2E = 1.4426950408889634f;
  const float kmul = (p == 2) ? (-2.0f * LOG2E) : (-LOG2E);
  const float smul = (p == 2) ? 2.0f : 1.0f;
  const float badd = (p == 2) ? -1.0f : 0.0f;
  const float KT2 = -2.0f * LOG2E;  // for tanh(c)

  if (t < 160) ((u32*)hbuf)[t] = 0u;  // zero both buffers (fp16 zero)
  float c = 0.0f;
  float hrelu_prev = 0.0f;
  float xz = XZ[p * 128 + elem];
  BAR();
  int cur = 0;
  for (int e = 0; e < STEPS; ++e) {
    // full h (128 fp16 = 64 u32) via 16 broadcast b128 reads; 64 dot2 in
    // 4 independent chains (disjoint k-subsets; sum = full dot product)
    const uint4* hb = (const uint4*)&hbuf[cur][0];
    float a0 = 0.0f, a1 = 0.0f, a2 = 0.0f, a3 = 0.0f;
#pragma unroll
    for (int q = 0; q < 16; ++q) {
      uint4 tv = hb[q];
      h2 h0, h1, h2_, h3;
      __builtin_memcpy(&h0, &tv.x, 4);
      __builtin_memcpy(&h1, &tv.y, 4);
      __builtin_memcpy(&h2_, &tv.z, 4);
      __builtin_memcpy(&h3, &tv.w, 4);
      a0 = fdot2_(w16[4 * q + 0], h0, a0);
      a1 = fdot2_(w16[4 * q + 1], h1, a1);
      a2 = fdot2_(w16[4 * q + 2], h2_, a2);
      a3 = fdot2_(w16[4 * q + 3], h3, a3);
    }
    float z = ((a0 + a1) + (a2 + a3)) + xz;
    // prefetch next step's xz (own gate only; vmcnt at next use)
    xz = XZ[(size_t)(e + 1) * 512 + p * 128 + elem];
    // unified per-lane gate nonlinearity
    float ex = __builtin_amdgcn_exp2f(z * kmul);
    float gq = __builtin_fmaf(smul, rcp_(1.0f + ex), badd);
    // assemble c,h (valid in p==0 lanes; others compute garbage, never read)
    float gf = dppmov<0xB1>(gq);  // sigmoid(zf) from lane^1
    float gt = dppmov<0x4E>(gq);  // tanh(zg)    from lane^2
    float go = dppmov<0x1B>(gq);  // sigmoid(zo) from lane^3
    c = __builtin_fmaf(gf, c, gq * gt);
    float ec = __builtin_amdgcn_exp2f(c * KT2);
    float th = __builtin_fmaf(2.0f, rcp_(1.0f + ec), -1.0f);
    float h = go * th;
    if (islead) {
      ((u16*)&hbuf[cur ^ 1][0])[elem] = (u16)pk2u(h, h);
      if (e > 0) hout[(size_t)(e - 1) * 128 + elem] = hrelu_prev;
      hrelu_prev = fmaxf(h, 0.0f);
    }
    BAR();
    cur ^= 1;
  }
  if (islead) hout[(size_t)(STEPS - 1) * 128 + elem] = hrelu_prev;
}

// ---------------------------------------------------------------------------
// K3: fused segment_min over edges + aggr projection (aggr never leaves the
// block). Block n: phase 1 (threads 0..127) computes aggr[n][j] = min over
// edges with eidx==n; phase 2 (all 256) does XZu[n] += Wih_u[:,64:192]@aggr.
// ---------------------------------------------------------------------------
__global__ __launch_bounds__(256) void k_aggminproj(
    const float* __restrict__ cva, const float* __restrict__ msg,
    const int* __restrict__ eidx, float* __restrict__ XZu) {
  const int n = blockIdx.x, tid = threadIdx.x;
  __shared__ float av[HM];
  if (tid < HM) {
    float m = __uint_as_float(0x7f800000u);  // +inf (segment_min identity)
    for (int e = 0; e < NEDGE; ++e) {
      if (eidx[e] == n) m = fminf(m, msg[(size_t)e * HM + tid]);
    }
    av[tid] = m;
  }
  __syncthreads();
  for (int j = tid; j < ZU; j += 256) {
    const float* wr = cva + O_WU + j * DU + FN;
    float acc = 0.0f;
#pragma unroll
    for (int k = 0; k < HM; ++k) acc += wr[k] * av[k];
    XZu[(size_t)n * ZU + j] += acc;
  }
}

// ---------------------------------------------------------------------------
// K5: fused (aggB computed in-block, never global).
// blocks [0,64): aggB[b] = segmin(upd) -> XZg[b] += Wih_g[:,0:128] @ aggB[b]
// blocks [64,128): chosen[b] -> XZa[b] = Wih_a[:,0:128] @ chosen[b] + biases
// ---------------------------------------------------------------------------
__global__ __launch_bounds__(256) void k_gproj(
    const float* __restrict__ cva, const float* __restrict__ upd,
    const int* __restrict__ bidx, const int* __restrict__ who,
    float* __restrict__ XZg, float* __restrict__ XZa) {
  const int blk = blockIdx.x, tid = threadIdx.x;
  __shared__ float buf[HU];
  __shared__ int satbw;
  if (blk < BG) {
    const int b = blk;
    if (tid < HU) {
      float m = __uint_as_float(0x7f800000u);
      for (int n = 0; n < NNODE; ++n) {
        if (bidx[n] == b) m = fminf(m, upd[(size_t)n * HU + tid]);
      }
      buf[tid] = m;
    }
    __syncthreads();
    if (tid < ZG) {
      const float* wr = cva + O_WG + tid * DG;
      float acc = 0.0f;
#pragma unroll
      for (int k = 0; k < HU; ++k) acc += wr[k] * buf[k];
      XZg[(size_t)b * ZG + tid] += acc;
    }
  } else {
    const int b = blk - BG;
    const int whoB = who[b];
    if (tid == 0) {
      int off = 0;
      for (int i = 0; i < NNODE; ++i) off += (bidx[i] < b) ? 1 : 0;
      const int adj = (whoB == 3) ? 2 : whoB;
      satbw = (b == 0) ? who[0] : (adj + off);
    }
    if (whoB == 3) {
      if (tid < HU) {
        float m = __uint_as_float(0x7f800000u);
        for (int n = 0; n < NNODE; ++n) {
          if (bidx[n] == b) m = fminf(m, upd[(size_t)n * HU + tid]);
        }
        buf[tid] = m;
      }
      __syncthreads();
    } else {
      __syncthreads();
      if (tid < HU) buf[tid] = upd[(size_t)satbw * HU + tid];
      __syncthreads();
    }
    if (tid < ZA) {
      const float* wr = cva + O_WA + tid * DA;
      float acc = cva[O_BA + tid];
#pragma unroll
      for (int k = 0; k < HU; ++k) acc += wr[k] * buf[k];
      XZa[(size_t)b * ZA + tid] = acc;
    }
  }
}

// ---------------------------------------------------------------------------
// K6: group LSTM chain (64 steps, H=64) + action chain + softmax + fp32 out.
// ---------------------------------------------------------------------------
__global__ __launch_bounds__(256, 2) void k_final(
    const float* __restrict__ cva, const float* __restrict__ XZg,
    const float* __restrict__ XZa, float* __restrict__ out) {
  const int j = threadIdx.x;
  __shared__ __align__(16) float hg[HG];
  __shared__ float zsg[ZG];
  __shared__ float grp[BG * HG];
  __shared__ float za[ZA];
  __shared__ float haL[HA];
  __shared__ float res[BG * HA];

  float wg[HG];
  {
    const float* wr = cva + O_WHG + j * HG;
#pragma unroll
    for (int k = 0; k < HG; ++k) wg[k] = wr[k];
  }
  if (j < HG) hg[j] = 0.0f;
  float cg = 0.0f;
  __syncthreads();
  for (int b = 0; b < BG; ++b) {
    float acc = XZg[(size_t)b * ZG + j];
#pragma unroll
    for (int k = 0; k < HG; ++k) acc += wg[k] * hg[k];
    zsg[j] = acc;
    __syncthreads();
    if (j < HG) {
      float zi = zsg[j], zf = zsg[HG + j], zg = zsg[2 * HG + j], zo = zsg[3 * HG + j];
      cg = sigf(zf) * cg + sigf(zi) * tanh_(zg);
      float h = sigf(zo) * tanh_(cg);
      hg[j] = h;
      grp[b * HG + j] = fmaxf(h, 0.0f);
    }
    __syncthreads();
  }

  float wa2[HG];
  float wha[HA];
  if (j < ZA) {
    const float* wr2 = cva + O_WA + j * DA + HU;
#pragma unroll
    for (int k = 0; k < HG; ++k) wa2[k] = wr2[k];
#pragma unroll
    for (int k = 0; k < HA; ++k) wha[k] = cva[O_WHA + j * HA + k];
  }
  if (j < HA) haL[j] = 0.0f;
  float ca = 0.0f;
  __syncthreads();
  for (int b = 0; b < BG; ++b) {
    if (j < ZA) {
      float acc = XZa[(size_t)b * ZA + j];
#pragma unroll
      for (int k = 0; k < HG; ++k) acc += wa2[k] * grp[b * HG + k];
#pragma unroll
      for (int k = 0; k < HA; ++k) acc += wha[k] * haL[k];
      za[j] = acc;
    }
    __syncthreads();
    if (j < HA) {
      float zi = za[j], zf = za[HA + j], zg = za[2 * HA + j], zo = za[3 * HA + j];
      ca = sigf(zf) * ca + sigf(zi) * tanh_(zg);
      float h = sigf(zo) * tanh_(ca);
      haL[j] = h;
      res[b * HA + j] = h;
    }
    __syncthreads();
  }
  if (j < BG) {
    float x0 = res[j * 4 + 0], x1 = res[j * 4 + 1];
    float x2 = res[j * 4 + 2], x3 = res[j * 4 + 3];
    float m = fmaxf(fmaxf(x0, x1), fmaxf(x2, x3));
    float e0 = __expf(x0 - m), e1 = __expf(x1 - m);
    float e2 = __expf(x2 - m), e3 = __expf(x3 - m);
    float s = e0 + e1 + e2 + e3;
    out[j * 4 + 0] = e0 / s;
    out[j * 4 + 1] = e1 / s;
    out[j * 4 + 2] = e2 / s;
    out[j * 4 + 3] = e3 / s;
  }
}

__global__ void k_zero(float* out) { out[threadIdx.x] = 0.0f; }

extern "C" void kernel_launch(void* const* d_in, const int* in_sizes, int n_in,
                              void* d_out, int out_size, void* d_ws, size_t ws_size,
                              hipStream_t stream) {
  const void* nodes = d_in[0];
  const void* gattr = d_in[1];
  const int* eidx  = (const int*)d_in[2];
  const int* nn    = (const int*)d_in[3];
  const int* ne    = (const int*)d_in[4];
  const int* bidx  = (const int*)d_in[5];
  const int* who   = (const int*)d_in[6];

  if (ws_size < (size_t)WS_FLOATS * 4) {
    k_zero<<<1, 256, 0, stream>>>((float*)d_out);
    return;
  }

  float* ws = (float*)d_ws;
  int* flagp = (int*)d_ws;
  float* cva = ws + CV;
  float* XZm = cva + O_XZM;
  float* XZu = cva + O_XZU;
  float* XZg = cva + O_XZG;
  float* XZa = cva + O_XZA;
  float* upd = cva + O_UPD;
  float* msg = XZm;  // overlay (delayed-store ordering; see k_chain comment)

  k_detect<<<1, 64, 0, stream>>>((const u32*)nodes, flagp);
  k_convert<<<(CONV_TOTAL + 255) / 256, 256, 0, stream>>>(
      nodes, gattr,
      d_in[7], d_in[8], d_in[9], d_in[10],
      d_in[11], d_in[12], d_in[13], d_in[14],
      d_in[15], d_in[16], d_in[17], d_in[18],
      d_in[19], d_in[20], d_in[21], d_in[22],
      flagp, cva);
  k_pre<<<NEDGE + NNODE + BG, 256, 0, stream>>>(cva, eidx, nn, ne, XZm, XZu, XZg);
  k_chain<NEDGE><<<1, 512, 0, stream>>>(cva + O_WHM, XZm, msg);
  k_aggminproj<<<NNODE, 256, 0, stream>>>(cva, msg, eidx, XZu);
  k_chain<NNODE><<<1, 512, 0, stream>>>(cva + O_WHU, XZu, upd);
  k_gproj<<<2 * BG, 256, 0, stream>>>(cva, upd, bidx, who, XZg, XZa);
  k_final<<<1, 256, 0, stream>>>(cva, XZg, XZa, (float*)d_out);
}